// Round 2
// baseline (1181.173 us; speedup 1.0000x reference)
//
#include <hip/hip_runtime.h>
#include <stdint.h>

#define Hh 12
#define Cc 768
#define Tt 576
#define BTC 1769472L
#define HI_ 24
#define WI_ 24

typedef unsigned int uint;
typedef unsigned short ushort;
typedef __attribute__((ext_vector_type(8))) short short8;
typedef __attribute__((ext_vector_type(4))) float f32x4;

__device__ __forceinline__ ushort f2b(float f) {
  uint u = __float_as_uint(f);
  u += 0x7FFFu + ((u >> 16) & 1u);
  return (ushort)(u >> 16);
}
__device__ __forceinline__ float b2f(ushort h) { return __uint_as_float(((uint)h) << 16); }
__device__ __forceinline__ float sigm(float x) { return 1.0f / (1.0f + __expf(-x)); }

// ---------- GEMM: C[M,N] = A[M,K] @ B[N,K]^T, fp32 in/out, bf16x3 internal ----------
// 64x64 tile, BK=32, 256 threads (4 waves = 2x2 quadrants of 32x32, 2x2 frags each).
// A,B are fp32; split into hi/lo bf16 in-kernel: acc += Ah*Bh + Ah*Bl + Al*Bh.
// Batched via blockIdx.z (element strides sA/sB/sC). M multiple of 64; N guarded.
__global__ __launch_bounds__(256) void gemm3(
    const float* __restrict__ A, const float* __restrict__ Bm, float* __restrict__ C,
    int N, int K, int lda, int ldb, int ldc, long sA, long sB, long sC) {
  A += (long)blockIdx.z * sA;
  Bm += (long)blockIdx.z * sB;
  C += (long)blockIdx.z * sC;
  __shared__ ushort Ah[64][36], Al[64][36], Bh[64][36], Bl[64][36];
  const int bm = blockIdx.x * 64, bn = blockIdx.y * 64;
  const int tid = threadIdx.x;
  const int wave = tid >> 6, lane = tid & 63;
  const int wm = (wave >> 1) * 32, wn = (wave & 1) * 32;
  const int srow = tid >> 2, scol = (tid & 3) * 8;
  const int fr = lane & 15, kg = (lane >> 4) * 8;
  f32x4 acc[2][2] = {};
  const int bnrow = bn + srow;
  const float* ap = A + (long)(bm + srow) * lda + scol;
  const float* bp = Bm + (long)bnrow * ldb + scol;
  for (int k0 = 0; k0 < K; k0 += 32) {
    f32x4 av0 = *(const f32x4*)(ap + k0);
    f32x4 av1 = *(const f32x4*)(ap + k0 + 4);
    f32x4 bv0 = {}, bv1 = {};
    if (bnrow < N) { bv0 = *(const f32x4*)(bp + k0); bv1 = *(const f32x4*)(bp + k0 + 4); }
    short8 a_h, a_l, b_h, b_l;
#pragma unroll
    for (int j = 0; j < 4; j++) {
      ushort h;
      h = f2b(av0[j]); a_h[j] = (short)h; a_l[j] = (short)f2b(av0[j] - b2f(h));
      h = f2b(av1[j]); a_h[j + 4] = (short)h; a_l[j + 4] = (short)f2b(av1[j] - b2f(h));
      h = f2b(bv0[j]); b_h[j] = (short)h; b_l[j] = (short)f2b(bv0[j] - b2f(h));
      h = f2b(bv1[j]); b_h[j + 4] = (short)h; b_l[j + 4] = (short)f2b(bv1[j] - b2f(h));
    }
    __syncthreads();
    *(short8*)&Ah[srow][scol] = a_h;
    *(short8*)&Al[srow][scol] = a_l;
    *(short8*)&Bh[srow][scol] = b_h;
    *(short8*)&Bl[srow][scol] = b_l;
    __syncthreads();
#pragma unroll
    for (int mi = 0; mi < 2; mi++) {
      short8 afh = *(const short8*)&Ah[wm + mi * 16 + fr][kg];
      short8 afl = *(const short8*)&Al[wm + mi * 16 + fr][kg];
#pragma unroll
      for (int ni = 0; ni < 2; ni++) {
        short8 bfh = *(const short8*)&Bh[wn + ni * 16 + fr][kg];
        short8 bfl = *(const short8*)&Bl[wn + ni * 16 + fr][kg];
        acc[mi][ni] = __builtin_amdgcn_mfma_f32_16x16x32_bf16(afh, bfh, acc[mi][ni], 0, 0, 0);
        acc[mi][ni] = __builtin_amdgcn_mfma_f32_16x16x32_bf16(afh, bfl, acc[mi][ni], 0, 0, 0);
        acc[mi][ni] = __builtin_amdgcn_mfma_f32_16x16x32_bf16(afl, bfh, acc[mi][ni], 0, 0, 0);
      }
    }
  }
  const int row4 = (lane >> 4) * 4;
#pragma unroll
  for (int mi = 0; mi < 2; mi++)
#pragma unroll
    for (int ni = 0; ni < 2; ni++) {
      int gc = bn + wn + ni * 16 + fr;
      if (gc < N) {
        long base = (long)(bm + wm + mi * 16 + row4) * ldc + gc;
#pragma unroll
        for (int rr = 0; rr < 4; rr++) C[base + (long)rr * ldc] = acc[mi][ni][rr];
      }
    }
}

// ---------- weight prep: fp32 transposes (and zero-pad) ----------
__global__ __launch_bounds__(256) void prep_smallw(
    const float* maa_w1, const float* maa_w2, const float* wd1, const float* wd2,
    const float* a1, const float* a2, const float* kk1, const float* kk2,
    const float* g1, const float* g2, const float* ma1, const float* ma2,
    const float* mk1, const float* mk2, float* w1T, float* w2T, float* wcat1,
    float* kk1T, float* g1T, float* wd2T, float* armk2T, float* g2T) {
  int idx = blockIdx.x * 256 + threadIdx.x;
  // 0: maa_w1 (768,128) -> w1T (128,768)
  if (idx < 98304) { int n = idx / 768, c = idx % 768; w1T[idx] = maa_w1[c * 128 + n]; return; }
  idx -= 98304;
  // 1: maa_w2 (4,32,768) -> w2T 4x(768,32)
  if (idx < 98304) {
    int f = idx / 24576, r = idx % 24576; int n = r / 32, d = r % 32;
    w2T[idx] = maa_w2[(f * 32 + d) * 768 + n]; return;
  }
  idx -= 98304;
  // 2: wd1 (768,64) -> wcat1 rows 0-63
  if (idx < 49152) { int n = idx / 768, c = idx % 768; wcat1[idx] = wd1[c * 64 + n]; return; }
  idx -= 49152;
  // 3: a1 -> rows 64-79
  if (idx < 12288) { int n = idx / 768, c = idx % 768; wcat1[49152 + idx] = a1[c * 16 + n]; return; }
  idx -= 12288;
  // 4: ma1 -> rows 80-95
  if (idx < 12288) { int n = idx / 768, c = idx % 768; wcat1[61440 + idx] = ma1[c * 16 + n]; return; }
  idx -= 12288;
  // 5: mk1 -> rows 96-111
  if (idx < 12288) { int n = idx / 768, c = idx % 768; wcat1[73728 + idx] = mk1[c * 16 + n]; return; }
  idx -= 12288;
  // 6: kk1 (768,16) -> kk1T (16,768)
  if (idx < 12288) { int n = idx / 768, c = idx % 768; kk1T[idx] = kk1[c * 16 + n]; return; }
  idx -= 12288;
  // 7: g1 (768,128) -> g1T (128,768)
  if (idx < 98304) { int n = idx / 768, c = idx % 768; g1T[idx] = g1[c * 128 + n]; return; }
  idx -= 98304;
  // 8: wd2 (64,768) -> wd2T (768,64)
  if (idx < 49152) { int n = idx / 64, d = idx % 64; wd2T[idx] = wd2[d * 768 + n]; return; }
  idx -= 49152;
  // 9: a2/ma2/mk2/kk2 (16,768) -> armk2T 4x(768,32) zero-padded K 16->32
  if (idx < 98304) {
    int f = idx / 24576, r = idx % 24576; int n = r / 32, d = r % 32;
    const float* s = (f == 0) ? a2 : (f == 1) ? ma2 : (f == 2) ? mk2 : kk2;
    armk2T[idx] = (d < 16) ? s[d * 768 + n] : 0.0f; return;
  }
  idx -= 98304;
  // 10: g2 (128,768) -> g2T (768,128)
  if (idx < 98304) { int n = idx / 128, d = idx % 128; g2T[idx] = g2[d * 768 + n]; }
}

// ---------- elementwise ----------
__global__ __launch_bounds__(256) void qshift_mix(const float* __restrict__ x,
                                                  const float* __restrict__ maa_x,
                                                  float* __restrict__ xx,
                                                  float* __restrict__ xxx) {
  long idx = (long)blockIdx.x * 256 + threadIdx.x;  // < BTC
  int c = (int)(idx % Cc);
  int bt = (int)(idx / Cc);
  int t = bt % Tt;
  int hh = t / WI_, ww = t % WI_;
  int q = c / 192;
  float s = 0.f;
  if (q == 0) { if (ww > 0) s = x[idx - Cc]; }
  else if (q == 1) { if (ww < WI_ - 1) s = x[idx + Cc]; }
  else if (q == 2) { if (hh > 0) s = x[idx - (long)WI_ * Cc]; }
  else { if (hh < HI_ - 1) s = x[idx + (long)WI_ * Cc]; }
  float xv = x[idx];
  float d = s - xv;
  xx[idx] = d;
  xxx[idx] = xv + d * maa_x[c];
}

__global__ __launch_bounds__(256) void tanh_f(const float* __restrict__ in,
                                              float* __restrict__ out) {
  int i = blockIdx.x * 256 + threadIdx.x;  // 2304*128
  out[i] = tanhf(in[i]);
}

__global__ __launch_bounds__(256) void mix4(const float* __restrict__ x,
                                            const float* __restrict__ xx,
                                            const float* __restrict__ m,
                                            const float* __restrict__ maa_rg,
                                            const float* __restrict__ maa_wa,
                                            const float* __restrict__ maa_k,
                                            const float* __restrict__ maa_v,
                                            float* __restrict__ x4) {
  long idx = (long)blockIdx.x * 256 + threadIdx.x;  // BTC
  int c = (int)(idx % Cc);
  float xv = x[idx], d = xx[idx];
  x4[idx] = xv + d * (maa_rg[c] + m[idx]);                    // xrg (m[0])
  x4[idx + BTC] = xv + d * (maa_k[c] + m[idx + 2 * BTC]);     // xk  (m[2])
  x4[idx + 2 * BTC] = xv + d * (maa_v[c] + m[idx + 3 * BTC]); // xv  (m[3])
  x4[idx + 3 * BTC] = xv + d * (maa_wa[c] + m[idx + BTC]);    // xwa (m[1])
}

__global__ __launch_bounds__(256) void build_a2(const float* __restrict__ wlora,
                                                const float* __restrict__ kklora,
                                                const float* __restrict__ glora,
                                                float* __restrict__ A2,
                                                float* __restrict__ glsig) {
  int idx = blockIdx.x * 256 + threadIdx.x;
  const int NA2 = 2304 * 160;
  if (idx < NA2) {
    int bt = idx / 160, col = idx % 160;
    float v;
    if (col < 64) v = tanhf(wlora[bt * 112 + col]);
    else if (col < 112) v = wlora[bt * 112 + col];
    else if (col < 128) v = tanhf(kklora[bt * 16 + (col - 112)]);
    else v = 0.0f;
    A2[idx] = v;
    return;
  }
  idx -= NA2;
  glsig[idx] = sigm(glora[idx]);  // 2304*128
}

// one wave per (bt,h); writes aa/bb/decay/k3 IN PLACE over araw/maraw/mkraw/kkraw.
__global__ __launch_bounds__(256) void post_rwkv(
    const float* __restrict__ k, const float* __restrict__ wraw, const float* __restrict__ w0,
    const float* __restrict__ a0, const float* __restrict__ ma0, const float* __restrict__ mk0,
    float* araw, float* maraw, float* mkraw, float* kkraw) {
  int gw = blockIdx.x * 4 + (threadIdx.x >> 6);  // 0..27647
  int j = threadIdx.x & 63;
  int bt = gw / Hh, h = gw % Hh;
  int c = h * 64 + j;
  long idx = (long)bt * Cc + c;
  float kv = k[idx];
  float kkv = kv + kkraw[idx];
  float ss = kkv * kkv;
  for (int mm = 1; mm < 64; mm <<= 1) ss += __shfl_xor(ss, mm, 64);
  float rn = 1.0f / fmaxf(sqrtf(ss), 1e-12f);
  float kkn = kkv * rn;
  float z = w0[c] + wraw[idx];
  float w = fminf(z, 0.f) - log1pf(__expf(-fabsf(z))) - 0.5f;
  float a = sigm(a0[c] + araw[idx]);
  float ma = sigm(ma0[c] + maraw[idx]);
  float mk = sigm(mk0[c] + mkraw[idx]);
  float k2 = kv * ma + kv * a * (1.f - ma);
  float k3 = k2 * __expf(fminf(w * mk, 0.f));
  araw[idx] = -kkn;          // aa
  maraw[idx] = kkn * a;      // bb
  mkraw[idx] = __expf(w);    // decay d
  kkraw[idx] = k3;           // final k
}

// ---------- WKV7: 48 blocks (one per (b,h)), 256 threads, state in registers ----------
__global__ __launch_bounds__(256) void wkv7(const float* __restrict__ r,
                                            const float* __restrict__ dd,
                                            const float* __restrict__ kk,
                                            const float* __restrict__ vv,
                                            const float* __restrict__ aa,
                                            const float* __restrict__ bb,
                                            float* __restrict__ y) {
  int bh = blockIdx.x;
  int b = bh / Hh, h = bh % Hh;
  int wave = threadIdx.x >> 6, lane = threadIdx.x & 63;
  int i = wave * 16 + (lane >> 2);
  int cb = (lane & 3) * 16;
  float S[16];
#pragma unroll
  for (int u = 0; u < 16; u++) S[u] = 0.f;
  long vecbase = ((long)b * Tt) * Cc + h * 64;
  for (int t = 0; t < Tt; t++) {
    long o = vecbase + (long)t * Cc + cb;
    f32x4 rv[4], dv[4], kv[4], av[4], bv[4];
#pragma unroll
    for (int u = 0; u < 4; u++) {
      rv[u] = *(const f32x4*)(r + o + u * 4);
      dv[u] = *(const f32x4*)(dd + o + u * 4);
      kv[u] = *(const f32x4*)(kk + o + u * 4);
      av[u] = *(const f32x4*)(aa + o + u * 4);
      bv[u] = *(const f32x4*)(bb + o + u * 4);
    }
    float vi = vv[vecbase + (long)t * Cc + i];
    float sa = 0.f;
#pragma unroll
    for (int u = 0; u < 4; u++)
#pragma unroll
      for (int e = 0; e < 4; e++) sa += S[u * 4 + e] * av[u][e];
    sa += __shfl_xor(sa, 1, 64);
    sa += __shfl_xor(sa, 2, 64);
    float yp = 0.f;
#pragma unroll
    for (int u = 0; u < 4; u++)
#pragma unroll
      for (int e = 0; e < 4; e++) {
        float s2 = S[u * 4 + e] * dv[u][e] + sa * bv[u][e] + vi * kv[u][e];
        S[u * 4 + e] = s2;
        yp += s2 * rv[u][e];
      }
    yp += __shfl_xor(yp, 1, 64);
    yp += __shfl_xor(yp, 2, 64);
    if ((lane & 3) == 0) y[vecbase + (long)t * Cc + i] = yp;
  }
}

// ---------- groupnorm + bonus + gate ----------
__global__ __launch_bounds__(256) void gn_bonus_gate(
    const float* __restrict__ y, const float* __restrict__ r, const float* __restrict__ k3,
    const float* __restrict__ v, const float* __restrict__ g, const float* __restrict__ faaaa,
    const float* __restrict__ lns, const float* __restrict__ lnb, float* __restrict__ yg) {
  int gw = blockIdx.x * 4 + (threadIdx.x >> 6);
  int j = threadIdx.x & 63;
  int bt = gw / Hh, h = gw % Hh;
  int c = h * 64 + j;
  long idx = (long)bt * Cc + c;
  float yv = y[idx];
  float s1 = yv, s2 = yv * yv;
  float s3 = r[idx] * k3[idx] * faaaa[c];
  for (int mm = 1; mm < 64; mm <<= 1) {
    s1 += __shfl_xor(s1, mm, 64);
    s2 += __shfl_xor(s2, mm, 64);
    s3 += __shfl_xor(s3, mm, 64);
  }
  float mu = s1 * (1.f / 64.f);
  float var = s2 * (1.f / 64.f) - mu * mu;
  float xn = (yv - mu) * rsqrtf(var + 64e-5f);
  float y2 = xn * lns[c] + lnb[c] + s3 * v[idx];
  yg[idx] = y2 * g[idx];
}

// ---------- launch ----------
extern "C" void kernel_launch(void* const* d_in, const int* in_sizes, int n_in,
                              void* d_out, int out_size, void* d_ws, size_t ws_size,
                              hipStream_t stream) {
  const float* x = (const float*)d_in[0];
  const float* maa_x = (const float*)d_in[1];
  const float* maa_rg = (const float*)d_in[2];
  const float* maa_wa = (const float*)d_in[3];
  const float* maa_k = (const float*)d_in[4];
  const float* maa_v = (const float*)d_in[5];
  const float* maa_w1 = (const float*)d_in[6];
  const float* maa_w2 = (const float*)d_in[7];
  const float* w0 = (const float*)d_in[8];
  const float* wd1 = (const float*)d_in[9];
  const float* wd2 = (const float*)d_in[10];
  const float* a0 = (const float*)d_in[11];
  const float* a1 = (const float*)d_in[12];
  const float* a2 = (const float*)d_in[13];
  const float* kk1 = (const float*)d_in[14];
  const float* kk2 = (const float*)d_in[15];
  const float* g1 = (const float*)d_in[16];
  const float* g2 = (const float*)d_in[17];
  const float* ma0 = (const float*)d_in[18];
  const float* ma1 = (const float*)d_in[19];
  const float* ma2 = (const float*)d_in[20];
  const float* mk0 = (const float*)d_in[21];
  const float* mk1 = (const float*)d_in[22];
  const float* mk2 = (const float*)d_in[23];
  const float* faaaa = (const float*)d_in[24];
  const float* Wr = (const float*)d_in[25];
  const float* Wk = (const float*)d_in[26];
  const float* Wv = (const float*)d_in[27];
  const float* Wo = (const float*)d_in[28];
  const float* lns = (const float*)d_in[29];
  const float* lnb = (const float*)d_in[30];

  float* fw = (float*)d_ws;
  float* xx = fw;                    // BTC (reused as yg at the end)
  float* xxx = fw + BTC;             // BTC (dead after lora gemm)
  float* m = fw + 2 * BTC;           // 4*BTC: m0..m3, later araw/maraw/mkraw/kkraw -> aa/bb/d/k3
  float* x4 = fw + 6 * BTC;          // 4*BTC: xrg,xk,xv,xwa
  float* rbuf = fw + 10 * BTC;
  float* kbuf = fw + 11 * BTC;
  float* vbuf = fw + 12 * BTC;
  float* wrawb = fw + 13 * BTC;
  float* gbuf = fw + 14 * BTC;
  float* ybuf = fw + 15 * BTC;
  float* lora_raw = fw + 16 * BTC;         // 294912
  float* lora_tanh = lora_raw + 294912;    // 294912
  float* wlora = lora_tanh + 294912;       // 258048
  float* glora = wlora + 258048;           // 294912
  float* kklora = glora + 294912;          // 36864
  float* A2f = kklora + 36864;             // 368640
  float* glsigf = A2f + 368640;            // 294912
  float* w1T = glsigf + 294912;            // 98304
  float* w2T = w1T + 98304;                // 98304
  float* wcat1 = w2T + 98304;              // 86016
  float* kk1T = wcat1 + 86016;             // 12288
  float* g1T = kk1T + 12288;               // 98304
  float* wd2T = g1T + 98304;               // 49152
  float* armk2T = wd2T + 49152;            // 98304
  float* g2T = armk2T + 98304;             // 98304
  float* yg = xx;

  dim3 blk(256);
  prep_smallw<<<2496, blk, 0, stream>>>(maa_w1, maa_w2, wd1, wd2, a1, a2, kk1, kk2, g1, g2,
                                        ma1, ma2, mk1, mk2, w1T, w2T, wcat1, kk1T, g1T, wd2T,
                                        armk2T, g2T);
  qshift_mix<<<6912, blk, 0, stream>>>(x, maa_x, xx, xxx);
  // lora_raw = xxx @ maa_w1  (N=128, K=768)
  gemm3<<<dim3(36, 2, 1), blk, 0, stream>>>(xxx, w1T, lora_raw, 128, 768, 768, 768, 128, 0, 0, 0);
  tanh_f<<<1152, blk, 0, stream>>>(lora_raw, lora_tanh);
  // m[f] = lora[:, f*32:+32] @ maa_w2[f]  (z=4, K=32)
  gemm3<<<dim3(36, 12, 4), blk, 0, stream>>>(lora_tanh, w2T, m, 768, 32, 128, 32, 768,
                                             32, 24576, BTC);
  mix4<<<6912, blk, 0, stream>>>(x, xx, m, maa_rg, maa_wa, maa_k, maa_v, x4);
  // r, k, v  (768x768, fp32 weights direct)
  gemm3<<<dim3(36, 12, 1), blk, 0, stream>>>(x4, Wr, rbuf, 768, 768, 768, 768, 768, 0, 0, 0);
  gemm3<<<dim3(36, 12, 1), blk, 0, stream>>>(x4 + BTC, Wk, kbuf, 768, 768, 768, 768, 768, 0, 0, 0);
  gemm3<<<dim3(36, 12, 1), blk, 0, stream>>>(x4 + 2 * BTC, Wv, vbuf, 768, 768, 768, 768, 768, 0, 0, 0);
  // wlora = xwa @ [wd1|a1|ma1|mk1]  (N=112)
  gemm3<<<dim3(36, 2, 1), blk, 0, stream>>>(x4 + 3 * BTC, wcat1, wlora, 112, 768, 768, 768, 112, 0, 0, 0);
  // glora = xrg @ g1  (N=128)
  gemm3<<<dim3(36, 2, 1), blk, 0, stream>>>(x4, g1T, glora, 128, 768, 768, 768, 128, 0, 0, 0);
  // kklora = xk @ kk1  (N=16)
  gemm3<<<dim3(36, 1, 1), blk, 0, stream>>>(x4 + BTC, kk1T, kklora, 16, 768, 768, 768, 16, 0, 0, 0);
  build_a2<<<2592, blk, 0, stream>>>(wlora, kklora, glora, A2f, glsigf);
  // wraw = tanh(wlora[:,0:64]) @ wd2  (K=64)
  gemm3<<<dim3(36, 12, 1), blk, 0, stream>>>(A2f, wd2T, wrawb, 768, 64, 160, 64, 768, 0, 0, 0);
  // araw/maraw/mkraw/kkraw  (z=4, K=32 zero-padded)
  gemm3<<<dim3(36, 12, 4), blk, 0, stream>>>(A2f + 64, armk2T, m, 768, 32, 160, 32, 768,
                                             16, 24576, BTC);
  // g = sigmoid(glora) @ g2  (K=128)
  gemm3<<<dim3(36, 12, 1), blk, 0, stream>>>(glsigf, g2T, gbuf, 768, 128, 128, 128, 768, 0, 0, 0);
  post_rwkv<<<6912, blk, 0, stream>>>(kbuf, wrawb, w0, a0, ma0, mk0,
                                      m, m + BTC, m + 2 * BTC, m + 3 * BTC);
  wkv7<<<48, blk, 0, stream>>>(rbuf, m + 2 * BTC, m + 3 * BTC, vbuf, m, m + BTC, ybuf);
  gn_bonus_gate<<<6912, blk, 0, stream>>>(ybuf, rbuf, m + 3 * BTC, vbuf, gbuf, faaaa,
                                          lns, lnb, yg);
  // out = (y*g) @ Wo
  gemm3<<<dim3(36, 12, 1), blk, 0, stream>>>(yg, Wo, (float*)d_out, 768, 768, 768, 768, 768, 0, 0, 0);
}

// Round 3
// 1037.228 us; speedup vs baseline: 1.1388x; 1.1388x over previous
//
#include <hip/hip_runtime.h>
#include <stdint.h>

#define Hh 12
#define Cc 768
#define Tt 576
#define BTC 1769472L
#define HI_ 24
#define WI_ 24

typedef unsigned int uint;
typedef unsigned short ushort;
typedef __attribute__((ext_vector_type(8))) short short8;
typedef __attribute__((ext_vector_type(4))) float f32x4;

__device__ __forceinline__ ushort f2b(float f) {
  uint u = __float_as_uint(f);
  u += 0x7FFFu + ((u >> 16) & 1u);
  return (ushort)(u >> 16);
}
__device__ __forceinline__ float b2f(ushort h) { return __uint_as_float(((uint)h) << 16); }
__device__ __forceinline__ float sigm(float x) { return 1.0f / (1.0f + __expf(-x)); }

// ---------- GEMM: C[M,N] = A[M,K] @ B[N,K]^T, fp32 in/out, bf16x3 internal ----------
__global__ __launch_bounds__(256) void gemm3(
    const float* __restrict__ A, const float* __restrict__ Bm, float* __restrict__ C,
    int N, int K, int lda, int ldb, int ldc, long sA, long sB, long sC) {
  A += (long)blockIdx.z * sA;
  Bm += (long)blockIdx.z * sB;
  C += (long)blockIdx.z * sC;
  __shared__ ushort Ah[64][36], Al[64][36], Bh[64][36], Bl[64][36];
  const int bm = blockIdx.x * 64, bn = blockIdx.y * 64;
  const int tid = threadIdx.x;
  const int wave = tid >> 6, lane = tid & 63;
  const int wm = (wave >> 1) * 32, wn = (wave & 1) * 32;
  const int srow = tid >> 2, scol = (tid & 3) * 8;
  const int fr = lane & 15, kg = (lane >> 4) * 8;
  f32x4 acc[2][2] = {};
  const int bnrow = bn + srow;
  const float* ap = A + (long)(bm + srow) * lda + scol;
  const float* bp = Bm + (long)bnrow * ldb + scol;
  for (int k0 = 0; k0 < K; k0 += 32) {
    f32x4 av0 = *(const f32x4*)(ap + k0);
    f32x4 av1 = *(const f32x4*)(ap + k0 + 4);
    f32x4 bv0 = {}, bv1 = {};
    if (bnrow < N) { bv0 = *(const f32x4*)(bp + k0); bv1 = *(const f32x4*)(bp + k0 + 4); }
    short8 a_h, a_l, b_h, b_l;
#pragma unroll
    for (int j = 0; j < 4; j++) {
      ushort h;
      h = f2b(av0[j]); a_h[j] = (short)h; a_l[j] = (short)f2b(av0[j] - b2f(h));
      h = f2b(av1[j]); a_h[j + 4] = (short)h; a_l[j + 4] = (short)f2b(av1[j] - b2f(h));
      h = f2b(bv0[j]); b_h[j] = (short)h; b_l[j] = (short)f2b(bv0[j] - b2f(h));
      h = f2b(bv1[j]); b_h[j + 4] = (short)h; b_l[j + 4] = (short)f2b(bv1[j] - b2f(h));
    }
    __syncthreads();
    *(short8*)&Ah[srow][scol] = a_h;
    *(short8*)&Al[srow][scol] = a_l;
    *(short8*)&Bh[srow][scol] = b_h;
    *(short8*)&Bl[srow][scol] = b_l;
    __syncthreads();
#pragma unroll
    for (int mi = 0; mi < 2; mi++) {
      short8 afh = *(const short8*)&Ah[wm + mi * 16 + fr][kg];
      short8 afl = *(const short8*)&Al[wm + mi * 16 + fr][kg];
#pragma unroll
      for (int ni = 0; ni < 2; ni++) {
        short8 bfh = *(const short8*)&Bh[wn + ni * 16 + fr][kg];
        short8 bfl = *(const short8*)&Bl[wn + ni * 16 + fr][kg];
        acc[mi][ni] = __builtin_amdgcn_mfma_f32_16x16x32_bf16(afh, bfh, acc[mi][ni], 0, 0, 0);
        acc[mi][ni] = __builtin_amdgcn_mfma_f32_16x16x32_bf16(afh, bfl, acc[mi][ni], 0, 0, 0);
        acc[mi][ni] = __builtin_amdgcn_mfma_f32_16x16x32_bf16(afl, bfh, acc[mi][ni], 0, 0, 0);
      }
    }
  }
  const int row4 = (lane >> 4) * 4;
#pragma unroll
  for (int mi = 0; mi < 2; mi++)
#pragma unroll
    for (int ni = 0; ni < 2; ni++) {
      int gc = bn + wn + ni * 16 + fr;
      if (gc < N) {
        long base = (long)(bm + wm + mi * 16 + row4) * ldc + gc;
#pragma unroll
        for (int rr = 0; rr < 4; rr++) C[base + (long)rr * ldc] = acc[mi][ni][rr];
      }
    }
}

// ---------- weight prep: fp32 transposes (and zero-pad) ----------
__global__ __launch_bounds__(256) void prep_smallw(
    const float* maa_w1, const float* maa_w2, const float* wd1, const float* wd2,
    const float* a1, const float* a2, const float* kk1, const float* kk2,
    const float* g1, const float* g2, const float* ma1, const float* ma2,
    const float* mk1, const float* mk2, float* w1T, float* w2T, float* wcat1,
    float* kk1T, float* g1T, float* wd2T, float* armk2T, float* g2T) {
  int idx = blockIdx.x * 256 + threadIdx.x;
  if (idx < 98304) { int n = idx / 768, c = idx % 768; w1T[idx] = maa_w1[c * 128 + n]; return; }
  idx -= 98304;
  if (idx < 98304) {
    int f = idx / 24576, r = idx % 24576; int n = r / 32, d = r % 32;
    w2T[idx] = maa_w2[(f * 32 + d) * 768 + n]; return;
  }
  idx -= 98304;
  if (idx < 49152) { int n = idx / 768, c = idx % 768; wcat1[idx] = wd1[c * 64 + n]; return; }
  idx -= 49152;
  if (idx < 12288) { int n = idx / 768, c = idx % 768; wcat1[49152 + idx] = a1[c * 16 + n]; return; }
  idx -= 12288;
  if (idx < 12288) { int n = idx / 768, c = idx % 768; wcat1[61440 + idx] = ma1[c * 16 + n]; return; }
  idx -= 12288;
  if (idx < 12288) { int n = idx / 768, c = idx % 768; wcat1[73728 + idx] = mk1[c * 16 + n]; return; }
  idx -= 12288;
  if (idx < 12288) { int n = idx / 768, c = idx % 768; kk1T[idx] = kk1[c * 16 + n]; return; }
  idx -= 12288;
  if (idx < 98304) { int n = idx / 768, c = idx % 768; g1T[idx] = g1[c * 128 + n]; return; }
  idx -= 98304;
  if (idx < 49152) { int n = idx / 64, d = idx % 64; wd2T[idx] = wd2[d * 768 + n]; return; }
  idx -= 49152;
  if (idx < 98304) {
    int f = idx / 24576, r = idx % 24576; int n = r / 32, d = r % 32;
    const float* s = (f == 0) ? a2 : (f == 1) ? ma2 : (f == 2) ? mk2 : kk2;
    armk2T[idx] = (d < 16) ? s[d * 768 + n] : 0.0f; return;
  }
  idx -= 98304;
  if (idx < 98304) { int n = idx / 128, d = idx % 128; g2T[idx] = g2[d * 768 + n]; }
}

// ---------- elementwise ----------
__global__ __launch_bounds__(256) void qshift_mix(const float* __restrict__ x,
                                                  const float* __restrict__ maa_x,
                                                  float* __restrict__ xx,
                                                  float* __restrict__ xxx) {
  long idx = (long)blockIdx.x * 256 + threadIdx.x;  // < BTC
  int c = (int)(idx % Cc);
  int bt = (int)(idx / Cc);
  int t = bt % Tt;
  int hh = t / WI_, ww = t % WI_;
  int q = c / 192;
  float s = 0.f;
  if (q == 0) { if (ww > 0) s = x[idx - Cc]; }
  else if (q == 1) { if (ww < WI_ - 1) s = x[idx + Cc]; }
  else if (q == 2) { if (hh > 0) s = x[idx - (long)WI_ * Cc]; }
  else { if (hh < HI_ - 1) s = x[idx + (long)WI_ * Cc]; }
  float xv = x[idx];
  float d = s - xv;
  xx[idx] = d;
  xxx[idx] = xv + d * maa_x[c];
}

__global__ __launch_bounds__(256) void tanh_f(const float* __restrict__ in,
                                              float* __restrict__ out) {
  int i = blockIdx.x * 256 + threadIdx.x;  // 2304*128
  out[i] = tanhf(in[i]);
}

__global__ __launch_bounds__(256) void mix4(const float* __restrict__ x,
                                            const float* __restrict__ xx,
                                            const float* __restrict__ m,
                                            const float* __restrict__ maa_rg,
                                            const float* __restrict__ maa_wa,
                                            const float* __restrict__ maa_k,
                                            const float* __restrict__ maa_v,
                                            float* __restrict__ x4) {
  long idx = (long)blockIdx.x * 256 + threadIdx.x;  // BTC
  int c = (int)(idx % Cc);
  float xv = x[idx], d = xx[idx];
  x4[idx] = xv + d * (maa_rg[c] + m[idx]);                    // xrg (m[0])
  x4[idx + BTC] = xv + d * (maa_k[c] + m[idx + 2 * BTC]);     // xk  (m[2])
  x4[idx + 2 * BTC] = xv + d * (maa_v[c] + m[idx + 3 * BTC]); // xv  (m[3])
  x4[idx + 3 * BTC] = xv + d * (maa_wa[c] + m[idx + BTC]);    // xwa (m[1])
}

__global__ __launch_bounds__(256) void build_a2(const float* __restrict__ wlora,
                                                const float* __restrict__ kklora,
                                                const float* __restrict__ glora,
                                                float* __restrict__ A2,
                                                float* __restrict__ glsig) {
  int idx = blockIdx.x * 256 + threadIdx.x;
  const int NA2 = 2304 * 160;
  if (idx < NA2) {
    int bt = idx / 160, col = idx % 160;
    float v;
    if (col < 64) v = tanhf(wlora[bt * 112 + col]);
    else if (col < 112) v = wlora[bt * 112 + col];
    else if (col < 128) v = tanhf(kklora[bt * 16 + (col - 112)]);
    else v = 0.0f;
    A2[idx] = v;
    return;
  }
  idx -= NA2;
  glsig[idx] = sigm(glora[idx]);  // 2304*128
}

// one wave per (bt,h); writes aa/bb/decay/k3 IN PLACE over araw/maraw/mkraw/kkraw.
__global__ __launch_bounds__(256) void post_rwkv(
    const float* __restrict__ k, const float* __restrict__ wraw, const float* __restrict__ w0,
    const float* __restrict__ a0, const float* __restrict__ ma0, const float* __restrict__ mk0,
    float* araw, float* maraw, float* mkraw, float* kkraw) {
  int gw = blockIdx.x * 4 + (threadIdx.x >> 6);  // 0..27647
  int j = threadIdx.x & 63;
  int bt = gw / Hh, h = gw % Hh;
  int c = h * 64 + j;
  long idx = (long)bt * Cc + c;
  float kv = k[idx];
  float kkv = kv + kkraw[idx];
  float ss = kkv * kkv;
  for (int mm = 1; mm < 64; mm <<= 1) ss += __shfl_xor(ss, mm, 64);
  float rn = 1.0f / fmaxf(sqrtf(ss), 1e-12f);
  float kkn = kkv * rn;
  float z = w0[c] + wraw[idx];
  float w = fminf(z, 0.f) - log1pf(__expf(-fabsf(z))) - 0.5f;
  float a = sigm(a0[c] + araw[idx]);
  float ma = sigm(ma0[c] + maraw[idx]);
  float mk = sigm(mk0[c] + mkraw[idx]);
  float k2 = kv * ma + kv * a * (1.f - ma);
  float k3 = k2 * __expf(fminf(w * mk, 0.f));
  araw[idx] = -kkn;          // aa
  maraw[idx] = kkn * a;      // bb
  mkraw[idx] = __expf(w);    // decay d
  kkraw[idx] = k3;           // final k
}

// ---------- WKV7: 48 blocks (one per (b,h)), 256 threads, state in registers ----------
// Software-pipelined: all 21 loads for step t+1 are issued before computing step t.
// __launch_bounds__(256,1): only 48 blocks exist; trade occupancy for registers.
__global__ __launch_bounds__(256, 1) void wkv7(const float* __restrict__ r,
                                               const float* __restrict__ dd,
                                               const float* __restrict__ kk,
                                               const float* __restrict__ vv,
                                               const float* __restrict__ aa,
                                               const float* __restrict__ bb,
                                               float* __restrict__ y) {
  int bh = blockIdx.x;
  int b = bh / Hh, h = bh % Hh;
  int wave = threadIdx.x >> 6, lane = threadIdx.x & 63;
  int i = wave * 16 + (lane >> 2);
  int cb = (lane & 3) * 16;
  float S[16];
#pragma unroll
  for (int u = 0; u < 16; u++) S[u] = 0.f;
  const long vecbase = ((long)b * Tt) * Cc + h * 64;
  const float* pr = r + vecbase + cb;
  const float* pd = dd + vecbase + cb;
  const float* pk = kk + vecbase + cb;
  const float* pa = aa + vecbase + cb;
  const float* pb = bb + vecbase + cb;
  const float* pv = vv + vecbase + i;
  float* py = y + vecbase + i;

  f32x4 Xr[4], Xd[4], Xk[4], Xa[4], Xb[4];
  float Xv;
  f32x4 Yr[4], Yd[4], Yk[4], Ya[4], Yb[4];
  float Yv;

#define WLOAD(R_, D_, K_, A_, B_, V_, off)            \
  {                                                   \
    _Pragma("unroll") for (int u = 0; u < 4; u++) {   \
      A_[u] = *(const f32x4*)(pa + (off) + u * 4);    \
      D_[u] = *(const f32x4*)(pd + (off) + u * 4);    \
      B_[u] = *(const f32x4*)(pb + (off) + u * 4);    \
      K_[u] = *(const f32x4*)(pk + (off) + u * 4);    \
      R_[u] = *(const f32x4*)(pr + (off) + u * 4);    \
    }                                                 \
    V_ = pv[off];                                     \
  }

#define WSTEP(R_, D_, K_, A_, B_, V_, off)                                   \
  {                                                                          \
    float p0 = S[0] * A_[0][0], p1 = S[1] * A_[0][1];                        \
    float p2 = S[2] * A_[0][2], p3 = S[3] * A_[0][3];                        \
    _Pragma("unroll") for (int u = 1; u < 4; u++) {                          \
      p0 += S[u * 4 + 0] * A_[u][0];                                         \
      p1 += S[u * 4 + 1] * A_[u][1];                                         \
      p2 += S[u * 4 + 2] * A_[u][2];                                         \
      p3 += S[u * 4 + 3] * A_[u][3];                                         \
    }                                                                        \
    float sa = (p0 + p1) + (p2 + p3);                                        \
    sa += __shfl_xor(sa, 1, 64);                                             \
    sa += __shfl_xor(sa, 2, 64);                                             \
    float q0 = 0.f, q1 = 0.f, q2 = 0.f, q3 = 0.f;                            \
    _Pragma("unroll") for (int u = 0; u < 4; u++) {                          \
      float s0 = S[u * 4 + 0] * D_[u][0] + sa * B_[u][0] + V_ * K_[u][0];    \
      float s1 = S[u * 4 + 1] * D_[u][1] + sa * B_[u][1] + V_ * K_[u][1];    \
      float s2 = S[u * 4 + 2] * D_[u][2] + sa * B_[u][2] + V_ * K_[u][2];    \
      float s3 = S[u * 4 + 3] * D_[u][3] + sa * B_[u][3] + V_ * K_[u][3];    \
      S[u * 4 + 0] = s0; S[u * 4 + 1] = s1;                                  \
      S[u * 4 + 2] = s2; S[u * 4 + 3] = s3;                                  \
      q0 += s0 * R_[u][0]; q1 += s1 * R_[u][1];                              \
      q2 += s2 * R_[u][2]; q3 += s3 * R_[u][3];                              \
    }                                                                        \
    float yp = (q0 + q1) + (q2 + q3);                                        \
    yp += __shfl_xor(yp, 1, 64);                                             \
    yp += __shfl_xor(yp, 2, 64);                                             \
    if ((lane & 3) == 0) py[off] = yp;                                       \
  }

  WLOAD(Xr, Xd, Xk, Xa, Xb, Xv, 0L);
  for (int t = 0; t < Tt; t += 2) {
    const long o1 = (long)(t + 1) * Cc;
    const long o2 = (long)(t + 2) * Cc;
    WLOAD(Yr, Yd, Yk, Ya, Yb, Yv, o1);   // prefetch t+1
    WSTEP(Xr, Xd, Xk, Xa, Xb, Xv, (long)t * Cc);
    WLOAD(Xr, Xd, Xk, Xa, Xb, Xv, o2);   // prefetch t+2 (last iter: 1-row OOB inside ws, unused)
    WSTEP(Yr, Yd, Yk, Ya, Yb, Yv, o1);
  }
#undef WLOAD
#undef WSTEP
}

// ---------- groupnorm + bonus + gate ----------
__global__ __launch_bounds__(256) void gn_bonus_gate(
    const float* __restrict__ y, const float* __restrict__ r, const float* __restrict__ k3,
    const float* __restrict__ v, const float* __restrict__ g, const float* __restrict__ faaaa,
    const float* __restrict__ lns, const float* __restrict__ lnb, float* __restrict__ yg) {
  int gw = blockIdx.x * 4 + (threadIdx.x >> 6);
  int j = threadIdx.x & 63;
  int bt = gw / Hh, h = gw % Hh;
  int c = h * 64 + j;
  long idx = (long)bt * Cc + c;
  float yv = y[idx];
  float s1 = yv, s2 = yv * yv;
  float s3 = r[idx] * k3[idx] * faaaa[c];
  for (int mm = 1; mm < 64; mm <<= 1) {
    s1 += __shfl_xor(s1, mm, 64);
    s2 += __shfl_xor(s2, mm, 64);
    s3 += __shfl_xor(s3, mm, 64);
  }
  float mu = s1 * (1.f / 64.f);
  float var = s2 * (1.f / 64.f) - mu * mu;
  float xn = (yv - mu) * rsqrtf(var + 64e-5f);
  float y2 = xn * lns[c] + lnb[c] + s3 * v[idx];
  yg[idx] = y2 * g[idx];
}

// ---------- launch ----------
extern "C" void kernel_launch(void* const* d_in, const int* in_sizes, int n_in,
                              void* d_out, int out_size, void* d_ws, size_t ws_size,
                              hipStream_t stream) {
  const float* x = (const float*)d_in[0];
  const float* maa_x = (const float*)d_in[1];
  const float* maa_rg = (const float*)d_in[2];
  const float* maa_wa = (const float*)d_in[3];
  const float* maa_k = (const float*)d_in[4];
  const float* maa_v = (const float*)d_in[5];
  const float* maa_w1 = (const float*)d_in[6];
  const float* maa_w2 = (const float*)d_in[7];
  const float* w0 = (const float*)d_in[8];
  const float* wd1 = (const float*)d_in[9];
  const float* wd2 = (const float*)d_in[10];
  const float* a0 = (const float*)d_in[11];
  const float* a1 = (const float*)d_in[12];
  const float* a2 = (const float*)d_in[13];
  const float* kk1 = (const float*)d_in[14];
  const float* kk2 = (const float*)d_in[15];
  const float* g1 = (const float*)d_in[16];
  const float* g2 = (const float*)d_in[17];
  const float* ma0 = (const float*)d_in[18];
  const float* ma1 = (const float*)d_in[19];
  const float* ma2 = (const float*)d_in[20];
  const float* mk0 = (const float*)d_in[21];
  const float* mk1 = (const float*)d_in[22];
  const float* mk2 = (const float*)d_in[23];
  const float* faaaa = (const float*)d_in[24];
  const float* Wr = (const float*)d_in[25];
  const float* Wk = (const float*)d_in[26];
  const float* Wv = (const float*)d_in[27];
  const float* Wo = (const float*)d_in[28];
  const float* lns = (const float*)d_in[29];
  const float* lnb = (const float*)d_in[30];

  float* fw = (float*)d_ws;
  float* xx = fw;                    // BTC (reused as yg at the end)
  float* xxx = fw + BTC;             // BTC
  float* m = fw + 2 * BTC;           // 4*BTC: m0..m3, later aa/bb/d/k3
  float* x4 = fw + 6 * BTC;          // 4*BTC: xrg,xk,xv,xwa
  float* rbuf = fw + 10 * BTC;
  float* kbuf = fw + 11 * BTC;
  float* vbuf = fw + 12 * BTC;
  float* wrawb = fw + 13 * BTC;
  float* gbuf = fw + 14 * BTC;
  float* ybuf = fw + 15 * BTC;
  float* lora_raw = fw + 16 * BTC;         // 294912
  float* lora_tanh = lora_raw + 294912;    // 294912
  float* wlora = lora_tanh + 294912;       // 258048
  float* glora = wlora + 258048;           // 294912
  float* kklora = glora + 294912;          // 36864
  float* A2f = kklora + 36864;             // 368640
  float* glsigf = A2f + 368640;            // 294912
  float* w1T = glsigf + 294912;            // 98304
  float* w2T = w1T + 98304;                // 98304
  float* wcat1 = w2T + 98304;              // 86016
  float* kk1T = wcat1 + 86016;             // 12288
  float* g1T = kk1T + 12288;               // 98304
  float* wd2T = g1T + 98304;               // 49152
  float* armk2T = wd2T + 49152;            // 98304
  float* g2T = armk2T + 98304;             // 98304
  float* yg = xx;

  dim3 blk(256);
  prep_smallw<<<2496, blk, 0, stream>>>(maa_w1, maa_w2, wd1, wd2, a1, a2, kk1, kk2, g1, g2,
                                        ma1, ma2, mk1, mk2, w1T, w2T, wcat1, kk1T, g1T, wd2T,
                                        armk2T, g2T);
  qshift_mix<<<6912, blk, 0, stream>>>(x, maa_x, xx, xxx);
  gemm3<<<dim3(36, 2, 1), blk, 0, stream>>>(xxx, w1T, lora_raw, 128, 768, 768, 768, 128, 0, 0, 0);
  tanh_f<<<1152, blk, 0, stream>>>(lora_raw, lora_tanh);
  gemm3<<<dim3(36, 12, 4), blk, 0, stream>>>(lora_tanh, w2T, m, 768, 32, 128, 32, 768,
                                             32, 24576, BTC);
  mix4<<<6912, blk, 0, stream>>>(x, xx, m, maa_rg, maa_wa, maa_k, maa_v, x4);
  gemm3<<<dim3(36, 12, 1), blk, 0, stream>>>(x4, Wr, rbuf, 768, 768, 768, 768, 768, 0, 0, 0);
  gemm3<<<dim3(36, 12, 1), blk, 0, stream>>>(x4 + BTC, Wk, kbuf, 768, 768, 768, 768, 768, 0, 0, 0);
  gemm3<<<dim3(36, 12, 1), blk, 0, stream>>>(x4 + 2 * BTC, Wv, vbuf, 768, 768, 768, 768, 768, 0, 0, 0);
  gemm3<<<dim3(36, 2, 1), blk, 0, stream>>>(x4 + 3 * BTC, wcat1, wlora, 112, 768, 768, 768, 112, 0, 0, 0);
  gemm3<<<dim3(36, 2, 1), blk, 0, stream>>>(x4, g1T, glora, 128, 768, 768, 768, 128, 0, 0, 0);
  gemm3<<<dim3(36, 1, 1), blk, 0, stream>>>(x4 + BTC, kk1T, kklora, 16, 768, 768, 768, 16, 0, 0, 0);
  build_a2<<<2592, blk, 0, stream>>>(wlora, kklora, glora, A2f, glsigf);
  gemm3<<<dim3(36, 12, 1), blk, 0, stream>>>(A2f, wd2T, wrawb, 768, 64, 160, 64, 768, 0, 0, 0);
  gemm3<<<dim3(36, 12, 4), blk, 0, stream>>>(A2f + 64, armk2T, m, 768, 32, 160, 32, 768,
                                             16, 24576, BTC);
  gemm3<<<dim3(36, 12, 1), blk, 0, stream>>>(glsigf, g2T, gbuf, 768, 128, 128, 128, 768, 0, 0, 0);
  post_rwkv<<<6912, blk, 0, stream>>>(kbuf, wrawb, w0, a0, ma0, mk0,
                                      m, m + BTC, m + 2 * BTC, m + 3 * BTC);
  wkv7<<<48, blk, 0, stream>>>(rbuf, m + 2 * BTC, m + 3 * BTC, vbuf, m, m + BTC, ybuf);
  gn_bonus_gate<<<6912, blk, 0, stream>>>(ybuf, rbuf, m + 3 * BTC, vbuf, gbuf, faaaa,
                                          lns, lnb, yg);
  gemm3<<<dim3(36, 12, 1), blk, 0, stream>>>(yg, Wo, (float*)d_out, 768, 768, 768, 768, 768, 0, 0, 0);
}

// Round 4
// 632.051 us; speedup vs baseline: 1.8688x; 1.6411x over previous
//
#include <hip/hip_runtime.h>
#include <stdint.h>

#define Hh 12
#define Cc 768
#define Tt 576
#define BTC 1769472L
#define HI_ 24
#define WI_ 24
#define CH 16
#define NCH 36

typedef unsigned int uint;
typedef unsigned short ushort;
typedef __attribute__((ext_vector_type(8))) short short8;
typedef __attribute__((ext_vector_type(4))) float f32x4;

__device__ __forceinline__ ushort f2b(float f) {
  uint u = __float_as_uint(f);
  u += 0x7FFFu + ((u >> 16) & 1u);
  return (ushort)(u >> 16);
}
__device__ __forceinline__ float b2f(ushort h) { return __uint_as_float(((uint)h) << 16); }
__device__ __forceinline__ float sigm(float x) { return 1.0f / (1.0f + __expf(-x)); }

// ---------- GEMM: C[M,N] = A[M,K] @ B[N,K]^T, fp32 in/out, bf16x3 internal ----------
__global__ __launch_bounds__(256) void gemm3(
    const float* __restrict__ A, const float* __restrict__ Bm, float* __restrict__ C,
    int N, int K, int lda, int ldb, int ldc, long sA, long sB, long sC) {
  A += (long)blockIdx.z * sA;
  Bm += (long)blockIdx.z * sB;
  C += (long)blockIdx.z * sC;
  __shared__ ushort Ah[64][36], Al[64][36], Bh[64][36], Bl[64][36];
  const int bm = blockIdx.x * 64, bn = blockIdx.y * 64;
  const int tid = threadIdx.x;
  const int wave = tid >> 6, lane = tid & 63;
  const int wm = (wave >> 1) * 32, wn = (wave & 1) * 32;
  const int srow = tid >> 2, scol = (tid & 3) * 8;
  const int fr = lane & 15, kg = (lane >> 4) * 8;
  f32x4 acc[2][2] = {};
  const int bnrow = bn + srow;
  const float* ap = A + (long)(bm + srow) * lda + scol;
  const float* bp = Bm + (long)bnrow * ldb + scol;
  for (int k0 = 0; k0 < K; k0 += 32) {
    f32x4 av0 = *(const f32x4*)(ap + k0);
    f32x4 av1 = *(const f32x4*)(ap + k0 + 4);
    f32x4 bv0 = {}, bv1 = {};
    if (bnrow < N) { bv0 = *(const f32x4*)(bp + k0); bv1 = *(const f32x4*)(bp + k0 + 4); }
    short8 a_h, a_l, b_h, b_l;
#pragma unroll
    for (int j = 0; j < 4; j++) {
      ushort h;
      h = f2b(av0[j]); a_h[j] = (short)h; a_l[j] = (short)f2b(av0[j] - b2f(h));
      h = f2b(av1[j]); a_h[j + 4] = (short)h; a_l[j + 4] = (short)f2b(av1[j] - b2f(h));
      h = f2b(bv0[j]); b_h[j] = (short)h; b_l[j] = (short)f2b(bv0[j] - b2f(h));
      h = f2b(bv1[j]); b_h[j + 4] = (short)h; b_l[j + 4] = (short)f2b(bv1[j] - b2f(h));
    }
    __syncthreads();
    *(short8*)&Ah[srow][scol] = a_h;
    *(short8*)&Al[srow][scol] = a_l;
    *(short8*)&Bh[srow][scol] = b_h;
    *(short8*)&Bl[srow][scol] = b_l;
    __syncthreads();
#pragma unroll
    for (int mi = 0; mi < 2; mi++) {
      short8 afh = *(const short8*)&Ah[wm + mi * 16 + fr][kg];
      short8 afl = *(const short8*)&Al[wm + mi * 16 + fr][kg];
#pragma unroll
      for (int ni = 0; ni < 2; ni++) {
        short8 bfh = *(const short8*)&Bh[wn + ni * 16 + fr][kg];
        short8 bfl = *(const short8*)&Bl[wn + ni * 16 + fr][kg];
        acc[mi][ni] = __builtin_amdgcn_mfma_f32_16x16x32_bf16(afh, bfh, acc[mi][ni], 0, 0, 0);
        acc[mi][ni] = __builtin_amdgcn_mfma_f32_16x16x32_bf16(afh, bfl, acc[mi][ni], 0, 0, 0);
        acc[mi][ni] = __builtin_amdgcn_mfma_f32_16x16x32_bf16(afl, bfh, acc[mi][ni], 0, 0, 0);
      }
    }
  }
  const int row4 = (lane >> 4) * 4;
#pragma unroll
  for (int mi = 0; mi < 2; mi++)
#pragma unroll
    for (int ni = 0; ni < 2; ni++) {
      int gc = bn + wn + ni * 16 + fr;
      if (gc < N) {
        long base = (long)(bm + wm + mi * 16 + row4) * ldc + gc;
#pragma unroll
        for (int rr = 0; rr < 4; rr++) C[base + (long)rr * ldc] = acc[mi][ni][rr];
      }
    }
}

// ---------- weight prep: fp32 transposes (and zero-pad) ----------
__global__ __launch_bounds__(256) void prep_smallw(
    const float* maa_w1, const float* maa_w2, const float* wd1, const float* wd2,
    const float* a1, const float* a2, const float* kk1, const float* kk2,
    const float* g1, const float* g2, const float* ma1, const float* ma2,
    const float* mk1, const float* mk2, float* w1T, float* w2T, float* wcat1,
    float* kk1T, float* g1T, float* wd2T, float* armk2T, float* g2T) {
  int idx = blockIdx.x * 256 + threadIdx.x;
  if (idx < 98304) { int n = idx / 768, c = idx % 768; w1T[idx] = maa_w1[c * 128 + n]; return; }
  idx -= 98304;
  if (idx < 98304) {
    int f = idx / 24576, r = idx % 24576; int n = r / 32, d = r % 32;
    w2T[idx] = maa_w2[(f * 32 + d) * 768 + n]; return;
  }
  idx -= 98304;
  if (idx < 49152) { int n = idx / 768, c = idx % 768; wcat1[idx] = wd1[c * 64 + n]; return; }
  idx -= 49152;
  if (idx < 12288) { int n = idx / 768, c = idx % 768; wcat1[49152 + idx] = a1[c * 16 + n]; return; }
  idx -= 12288;
  if (idx < 12288) { int n = idx / 768, c = idx % 768; wcat1[61440 + idx] = ma1[c * 16 + n]; return; }
  idx -= 12288;
  if (idx < 12288) { int n = idx / 768, c = idx % 768; wcat1[73728 + idx] = mk1[c * 16 + n]; return; }
  idx -= 12288;
  if (idx < 12288) { int n = idx / 768, c = idx % 768; kk1T[idx] = kk1[c * 16 + n]; return; }
  idx -= 12288;
  if (idx < 98304) { int n = idx / 768, c = idx % 768; g1T[idx] = g1[c * 128 + n]; return; }
  idx -= 98304;
  if (idx < 49152) { int n = idx / 64, d = idx % 64; wd2T[idx] = wd2[d * 768 + n]; return; }
  idx -= 49152;
  if (idx < 98304) {
    int f = idx / 24576, r = idx % 24576; int n = r / 32, d = r % 32;
    const float* s = (f == 0) ? a2 : (f == 1) ? ma2 : (f == 2) ? mk2 : kk2;
    armk2T[idx] = (d < 16) ? s[d * 768 + n] : 0.0f; return;
  }
  idx -= 98304;
  if (idx < 98304) { int n = idx / 128, d = idx % 128; g2T[idx] = g2[d * 768 + n]; }
}

// ---------- elementwise ----------
__global__ __launch_bounds__(256) void qshift_mix(const float* __restrict__ x,
                                                  const float* __restrict__ maa_x,
                                                  float* __restrict__ xx,
                                                  float* __restrict__ xxx) {
  long idx = (long)blockIdx.x * 256 + threadIdx.x;  // < BTC
  int c = (int)(idx % Cc);
  int bt = (int)(idx / Cc);
  int t = bt % Tt;
  int hh = t / WI_, ww = t % WI_;
  int q = c / 192;
  float s = 0.f;
  if (q == 0) { if (ww > 0) s = x[idx - Cc]; }
  else if (q == 1) { if (ww < WI_ - 1) s = x[idx + Cc]; }
  else if (q == 2) { if (hh > 0) s = x[idx - (long)WI_ * Cc]; }
  else { if (hh < HI_ - 1) s = x[idx + (long)WI_ * Cc]; }
  float xv = x[idx];
  float d = s - xv;
  xx[idx] = d;
  xxx[idx] = xv + d * maa_x[c];
}

__global__ __launch_bounds__(256) void tanh_f(const float* __restrict__ in,
                                              float* __restrict__ out) {
  int i = blockIdx.x * 256 + threadIdx.x;  // 2304*128
  out[i] = tanhf(in[i]);
}

__global__ __launch_bounds__(256) void mix4(const float* __restrict__ x,
                                            const float* __restrict__ xx,
                                            const float* __restrict__ m,
                                            const float* __restrict__ maa_rg,
                                            const float* __restrict__ maa_wa,
                                            const float* __restrict__ maa_k,
                                            const float* __restrict__ maa_v,
                                            float* __restrict__ x4) {
  long idx = (long)blockIdx.x * 256 + threadIdx.x;  // BTC
  int c = (int)(idx % Cc);
  float xv = x[idx], d = xx[idx];
  x4[idx] = xv + d * (maa_rg[c] + m[idx]);                    // xrg (m[0])
  x4[idx + BTC] = xv + d * (maa_k[c] + m[idx + 2 * BTC]);     // xk  (m[2])
  x4[idx + 2 * BTC] = xv + d * (maa_v[c] + m[idx + 3 * BTC]); // xv  (m[3])
  x4[idx + 3 * BTC] = xv + d * (maa_wa[c] + m[idx + BTC]);    // xwa (m[1])
}

__global__ __launch_bounds__(256) void build_a2(const float* __restrict__ wlora,
                                                const float* __restrict__ kklora,
                                                const float* __restrict__ glora,
                                                float* __restrict__ A2,
                                                float* __restrict__ glsig) {
  int idx = blockIdx.x * 256 + threadIdx.x;
  const int NA2 = 2304 * 160;
  if (idx < NA2) {
    int bt = idx / 160, col = idx % 160;
    float v;
    if (col < 64) v = tanhf(wlora[bt * 112 + col]);
    else if (col < 112) v = wlora[bt * 112 + col];
    else if (col < 128) v = tanhf(kklora[bt * 16 + (col - 112)]);
    else v = 0.0f;
    A2[idx] = v;
    return;
  }
  idx -= NA2;
  glsig[idx] = sigm(glora[idx]);  // 2304*128
}

// one wave per (bt,h); writes aa/bb/decay/k3 IN PLACE over araw/maraw/mkraw/kkraw.
__global__ __launch_bounds__(256) void post_rwkv(
    const float* __restrict__ k, const float* __restrict__ wraw, const float* __restrict__ w0,
    const float* __restrict__ a0, const float* __restrict__ ma0, const float* __restrict__ mk0,
    float* araw, float* maraw, float* mkraw, float* kkraw) {
  int gw = blockIdx.x * 4 + (threadIdx.x >> 6);  // 0..27647
  int j = threadIdx.x & 63;
  int bt = gw / Hh, h = gw % Hh;
  int c = h * 64 + j;
  long idx = (long)bt * Cc + c;
  float kv = k[idx];
  float kkv = kv + kkraw[idx];
  float ss = kkv * kkv;
  for (int mm = 1; mm < 64; mm <<= 1) ss += __shfl_xor(ss, mm, 64);
  float rn = 1.0f / fmaxf(sqrtf(ss), 1e-12f);
  float kkn = kkv * rn;
  float z = w0[c] + wraw[idx];
  float w = fminf(z, 0.f) - log1pf(__expf(-fabsf(z))) - 0.5f;
  float a = sigm(a0[c] + araw[idx]);
  float ma = sigm(ma0[c] + maraw[idx]);
  float mk = sigm(mk0[c] + mkraw[idx]);
  float k2 = kv * ma + kv * a * (1.f - ma);
  float k3 = k2 * __expf(fminf(w * mk, 0.f));
  araw[idx] = -kkn;          // aa
  maraw[idx] = kkn * a;      // bb
  mkraw[idx] = __expf(w);    // decay d
  kkraw[idx] = k3;           // final k
}

// ---------- WKV7: 48 blocks, 256 threads, LDS chunk double-buffer ----------
// wave owns rows [wave*16, +16); lane>>2 = row in wave, (lane&3)*16 = column block.
// CH=16 steps staged per buffer: 6 arrays (r,d,k,a,b,v) x 16 t x 64 c = 24KB; x2 = 48KB.
// T14 split: next chunk's global loads issued BEFORE compute, ds_write after barrier.
__global__ __launch_bounds__(256, 1) void wkv7(const float* __restrict__ r,
                                               const float* __restrict__ dd,
                                               const float* __restrict__ kk,
                                               const float* __restrict__ vv,
                                               const float* __restrict__ aa,
                                               const float* __restrict__ bb,
                                               float* __restrict__ y) {
  __shared__ float sbuf[2][6][CH][64];
  const int bh = blockIdx.x;
  const int b = bh / Hh, h = bh % Hh;
  const int wave = threadIdx.x >> 6, lane = threadIdx.x & 63;
  const int i = wave * 16 + (lane >> 2);
  const int cb = (lane & 3) * 16;
  const int tl = threadIdx.x >> 4;          // staging: t within chunk
  const int cg = (threadIdx.x & 15) * 4;    // staging: column group
  float S[16];
#pragma unroll
  for (int u = 0; u < 16; u++) S[u] = 0.f;
  const long base = ((long)b * Tt) * Cc + h * 64;
  float* py = y + base + i;

  f32x4 st0, st1, st2, st3, st4, st5;
#define SLOAD(t0)                                                  \
  {                                                                \
    const long so = base + (long)((t0) + tl) * Cc + cg;            \
    st0 = *(const f32x4*)(r + so);                                 \
    st1 = *(const f32x4*)(dd + so);                                \
    st2 = *(const f32x4*)(kk + so);                                \
    st3 = *(const f32x4*)(aa + so);                                \
    st4 = *(const f32x4*)(bb + so);                                \
    st5 = *(const f32x4*)(vv + so);                                \
  }
#define SWRITE(bi)                                                 \
  {                                                                \
    *(f32x4*)&sbuf[bi][0][tl][cg] = st0;                           \
    *(f32x4*)&sbuf[bi][1][tl][cg] = st1;                           \
    *(f32x4*)&sbuf[bi][2][tl][cg] = st2;                           \
    *(f32x4*)&sbuf[bi][3][tl][cg] = st3;                           \
    *(f32x4*)&sbuf[bi][4][tl][cg] = st4;                           \
    *(f32x4*)&sbuf[bi][5][tl][cg] = st5;                           \
  }
#define LREAD(R_, D_, K_, A_, B_, V_, bi, t)                       \
  {                                                                \
    _Pragma("unroll") for (int u = 0; u < 4; u++) {                \
      R_[u] = *(const f32x4*)&sbuf[bi][0][t][cb + u * 4];          \
      D_[u] = *(const f32x4*)&sbuf[bi][1][t][cb + u * 4];          \
      K_[u] = *(const f32x4*)&sbuf[bi][2][t][cb + u * 4];          \
      A_[u] = *(const f32x4*)&sbuf[bi][3][t][cb + u * 4];          \
      B_[u] = *(const f32x4*)&sbuf[bi][4][t][cb + u * 4];          \
    }                                                              \
    V_ = sbuf[bi][5][t][i];                                        \
  }
#define WSTEP(R_, D_, K_, A_, B_, V_, yoff)                                  \
  {                                                                          \
    float p0 = S[0] * A_[0][0], p1 = S[1] * A_[0][1];                        \
    float p2 = S[2] * A_[0][2], p3 = S[3] * A_[0][3];                        \
    _Pragma("unroll") for (int u = 1; u < 4; u++) {                          \
      p0 += S[u * 4 + 0] * A_[u][0];                                         \
      p1 += S[u * 4 + 1] * A_[u][1];                                         \
      p2 += S[u * 4 + 2] * A_[u][2];                                         \
      p3 += S[u * 4 + 3] * A_[u][3];                                         \
    }                                                                        \
    float sa = (p0 + p1) + (p2 + p3);                                        \
    sa += __shfl_xor(sa, 1, 64);                                             \
    sa += __shfl_xor(sa, 2, 64);                                             \
    float q0 = 0.f, q1 = 0.f, q2 = 0.f, q3 = 0.f;                            \
    _Pragma("unroll") for (int u = 0; u < 4; u++) {                          \
      float s0 = S[u * 4 + 0] * D_[u][0] + sa * B_[u][0] + V_ * K_[u][0];    \
      float s1 = S[u * 4 + 1] * D_[u][1] + sa * B_[u][1] + V_ * K_[u][1];    \
      float s2 = S[u * 4 + 2] * D_[u][2] + sa * B_[u][2] + V_ * K_[u][2];    \
      float s3 = S[u * 4 + 3] * D_[u][3] + sa * B_[u][3] + V_ * K_[u][3];    \
      S[u * 4 + 0] = s0; S[u * 4 + 1] = s1;                                  \
      S[u * 4 + 2] = s2; S[u * 4 + 3] = s3;                                  \
      q0 += s0 * R_[u][0]; q1 += s1 * R_[u][1];                              \
      q2 += s2 * R_[u][2]; q3 += s3 * R_[u][3];                              \
    }                                                                        \
    float yp = (q0 + q1) + (q2 + q3);                                        \
    yp += __shfl_xor(yp, 1, 64);                                             \
    yp += __shfl_xor(yp, 2, 64);                                             \
    if ((lane & 3) == 0) py[yoff] = yp;                                      \
  }

  // prologue: stage chunk 0, issue chunk 1 loads
  SLOAD(0);
  SWRITE(0);
  __syncthreads();
  SLOAD(CH);

  f32x4 Xr[4], Xd[4], Xk[4], Xa[4], Xb[4];
  f32x4 Yr[4], Yd[4], Yk[4], Ya[4], Yb[4];
  float Xv, Yv;

  for (int ch = 0; ch < NCH; ch++) {
    const int pb = ch & 1;
    const long tbase = (long)ch * CH * Cc;
    LREAD(Xr, Xd, Xk, Xa, Xb, Xv, pb, 0);
#pragma unroll
    for (int t = 0; t < CH; t += 2) {
      LREAD(Yr, Yd, Yk, Ya, Yb, Yv, pb, t + 1);
      WSTEP(Xr, Xd, Xk, Xa, Xb, Xv, tbase + (long)t * Cc);
      LREAD(Xr, Xd, Xk, Xa, Xb, Xv, pb, (t + 2 < CH) ? t + 2 : 0);  // tail: dummy re-read
      WSTEP(Yr, Yd, Yk, Ya, Yb, Yv, tbase + (long)(t + 1) * Cc);
    }
    __syncthreads();
    if (ch + 1 < NCH) {
      SWRITE(pb ^ 1);  // write prefetched chunk ch+1 (loads issued a whole chunk ago)
      if (ch + 2 < NCH) SLOAD((ch + 2) * CH);
    }
    __syncthreads();
  }
#undef SLOAD
#undef SWRITE
#undef LREAD
#undef WSTEP
}

// ---------- groupnorm + bonus + gate ----------
__global__ __launch_bounds__(256) void gn_bonus_gate(
    const float* __restrict__ y, const float* __restrict__ r, const float* __restrict__ k3,
    const float* __restrict__ v, const float* __restrict__ g, const float* __restrict__ faaaa,
    const float* __restrict__ lns, const float* __restrict__ lnb, float* __restrict__ yg) {
  int gw = blockIdx.x * 4 + (threadIdx.x >> 6);
  int j = threadIdx.x & 63;
  int bt = gw / Hh, h = gw % Hh;
  int c = h * 64 + j;
  long idx = (long)bt * Cc + c;
  float yv = y[idx];
  float s1 = yv, s2 = yv * yv;
  float s3 = r[idx] * k3[idx] * faaaa[c];
  for (int mm = 1; mm < 64; mm <<= 1) {
    s1 += __shfl_xor(s1, mm, 64);
    s2 += __shfl_xor(s2, mm, 64);
    s3 += __shfl_xor(s3, mm, 64);
  }
  float mu = s1 * (1.f / 64.f);
  float var = s2 * (1.f / 64.f) - mu * mu;
  float xn = (yv - mu) * rsqrtf(var + 64e-5f);
  float y2 = xn * lns[c] + lnb[c] + s3 * v[idx];
  yg[idx] = y2 * g[idx];
}

// ---------- launch ----------
extern "C" void kernel_launch(void* const* d_in, const int* in_sizes, int n_in,
                              void* d_out, int out_size, void* d_ws, size_t ws_size,
                              hipStream_t stream) {
  const float* x = (const float*)d_in[0];
  const float* maa_x = (const float*)d_in[1];
  const float* maa_rg = (const float*)d_in[2];
  const float* maa_wa = (const float*)d_in[3];
  const float* maa_k = (const float*)d_in[4];
  const float* maa_v = (const float*)d_in[5];
  const float* maa_w1 = (const float*)d_in[6];
  const float* maa_w2 = (const float*)d_in[7];
  const float* w0 = (const float*)d_in[8];
  const float* wd1 = (const float*)d_in[9];
  const float* wd2 = (const float*)d_in[10];
  const float* a0 = (const float*)d_in[11];
  const float* a1 = (const float*)d_in[12];
  const float* a2 = (const float*)d_in[13];
  const float* kk1 = (const float*)d_in[14];
  const float* kk2 = (const float*)d_in[15];
  const float* g1 = (const float*)d_in[16];
  const float* g2 = (const float*)d_in[17];
  const float* ma0 = (const float*)d_in[18];
  const float* ma1 = (const float*)d_in[19];
  const float* ma2 = (const float*)d_in[20];
  const float* mk0 = (const float*)d_in[21];
  const float* mk1 = (const float*)d_in[22];
  const float* mk2 = (const float*)d_in[23];
  const float* faaaa = (const float*)d_in[24];
  const float* Wr = (const float*)d_in[25];
  const float* Wk = (const float*)d_in[26];
  const float* Wv = (const float*)d_in[27];
  const float* Wo = (const float*)d_in[28];
  const float* lns = (const float*)d_in[29];
  const float* lnb = (const float*)d_in[30];

  float* fw = (float*)d_ws;
  float* xx = fw;                    // BTC (reused as yg at the end)
  float* xxx = fw + BTC;             // BTC
  float* m = fw + 2 * BTC;           // 4*BTC: m0..m3, later aa/bb/d/k3
  float* x4 = fw + 6 * BTC;          // 4*BTC: xrg,xk,xv,xwa
  float* rbuf = fw + 10 * BTC;
  float* kbuf = fw + 11 * BTC;
  float* vbuf = fw + 12 * BTC;
  float* wrawb = fw + 13 * BTC;
  float* gbuf = fw + 14 * BTC;
  float* ybuf = fw + 15 * BTC;
  float* lora_raw = fw + 16 * BTC;         // 294912
  float* lora_tanh = lora_raw + 294912;    // 294912
  float* wlora = lora_tanh + 294912;       // 258048
  float* glora = wlora + 258048;           // 294912
  float* kklora = glora + 294912;          // 36864
  float* A2f = kklora + 36864;             // 368640
  float* glsigf = A2f + 368640;            // 294912
  float* w1T = glsigf + 294912;            // 98304
  float* w2T = w1T + 98304;                // 98304
  float* wcat1 = w2T + 98304;              // 86016
  float* kk1T = wcat1 + 86016;             // 12288
  float* g1T = kk1T + 12288;               // 98304
  float* wd2T = g1T + 98304;               // 49152
  float* armk2T = wd2T + 49152;            // 98304
  float* g2T = armk2T + 98304;             // 98304
  float* yg = xx;

  dim3 blk(256);
  prep_smallw<<<2496, blk, 0, stream>>>(maa_w1, maa_w2, wd1, wd2, a1, a2, kk1, kk2, g1, g2,
                                        ma1, ma2, mk1, mk2, w1T, w2T, wcat1, kk1T, g1T, wd2T,
                                        armk2T, g2T);
  qshift_mix<<<6912, blk, 0, stream>>>(x, maa_x, xx, xxx);
  gemm3<<<dim3(36, 2, 1), blk, 0, stream>>>(xxx, w1T, lora_raw, 128, 768, 768, 768, 128, 0, 0, 0);
  tanh_f<<<1152, blk, 0, stream>>>(lora_raw, lora_tanh);
  gemm3<<<dim3(36, 12, 4), blk, 0, stream>>>(lora_tanh, w2T, m, 768, 32, 128, 32, 768,
                                             32, 24576, BTC);
  mix4<<<6912, blk, 0, stream>>>(x, xx, m, maa_rg, maa_wa, maa_k, maa_v, x4);
  gemm3<<<dim3(36, 12, 1), blk, 0, stream>>>(x4, Wr, rbuf, 768, 768, 768, 768, 768, 0, 0, 0);
  gemm3<<<dim3(36, 12, 1), blk, 0, stream>>>(x4 + BTC, Wk, kbuf, 768, 768, 768, 768, 768, 0, 0, 0);
  gemm3<<<dim3(36, 12, 1), blk, 0, stream>>>(x4 + 2 * BTC, Wv, vbuf, 768, 768, 768, 768, 768, 0, 0, 0);
  gemm3<<<dim3(36, 2, 1), blk, 0, stream>>>(x4 + 3 * BTC, wcat1, wlora, 112, 768, 768, 768, 112, 0, 0, 0);
  gemm3<<<dim3(36, 2, 1), blk, 0, stream>>>(x4, g1T, glora, 128, 768, 768, 768, 128, 0, 0, 0);
  gemm3<<<dim3(36, 1, 1), blk, 0, stream>>>(x4 + BTC, kk1T, kklora, 16, 768, 768, 768, 16, 0, 0, 0);
  build_a2<<<2592, blk, 0, stream>>>(wlora, kklora, glora, A2f, glsigf);
  gemm3<<<dim3(36, 12, 1), blk, 0, stream>>>(A2f, wd2T, wrawb, 768, 64, 160, 64, 768, 0, 0, 0);
  gemm3<<<dim3(36, 12, 4), blk, 0, stream>>>(A2f + 64, armk2T, m, 768, 32, 160, 32, 768,
                                             16, 24576, BTC);
  gemm3<<<dim3(36, 12, 1), blk, 0, stream>>>(glsigf, g2T, gbuf, 768, 128, 128, 128, 768, 0, 0, 0);
  post_rwkv<<<6912, blk, 0, stream>>>(kbuf, wrawb, w0, a0, ma0, mk0,
                                      m, m + BTC, m + 2 * BTC, m + 3 * BTC);
  wkv7<<<48, blk, 0, stream>>>(rbuf, m + 2 * BTC, m + 3 * BTC, vbuf, m, m + BTC, ybuf);
  gn_bonus_gate<<<6912, blk, 0, stream>>>(ybuf, rbuf, m + 3 * BTC, vbuf, gbuf, faaaa,
                                          lns, lnb, yg);
  gemm3<<<dim3(36, 12, 1), blk, 0, stream>>>(yg, Wo, (float*)d_out, 768, 768, 768, 768, 768, 0, 0, 0);
}

// Round 5
// 622.148 us; speedup vs baseline: 1.8985x; 1.0159x over previous
//
#include <hip/hip_runtime.h>
#include <stdint.h>

#define Hh 12
#define Cc 768
#define Tt 576
#define BTC 1769472L
#define HI_ 24
#define WI_ 24
#define CH 16
#define NCH 36

typedef unsigned int uint;
typedef unsigned short ushort;
typedef __attribute__((ext_vector_type(8))) short short8;
typedef __attribute__((ext_vector_type(4))) float f32x4;

__device__ __forceinline__ ushort f2b(float f) {
  uint u = __float_as_uint(f);
  u += 0x7FFFu + ((u >> 16) & 1u);
  return (ushort)(u >> 16);
}
__device__ __forceinline__ float b2f(ushort h) { return __uint_as_float(((uint)h) << 16); }
__device__ __forceinline__ float sigm(float x) { return 1.0f / (1.0f + __expf(-x)); }

// hi/lo convention: every bf16-split buffer holds hi plane at [0, SZ) and lo plane at [SZ, 2*SZ).
#define PUT2(buf, i, SZ, vexpr)                      \
  {                                                  \
    float _v = (vexpr);                              \
    ushort _h = f2b(_v);                             \
    (buf)[i] = _h;                                   \
    (buf)[(long)(SZ) + (i)] = f2b(_v - b2f(_h));     \
  }

// ---------- GEMM: C[M,N] = A[M,K] @ B[N,K]^T; A,B pre-split bf16 hi/lo; C fp32 ----------
// 64x64 tile, BK=32, 256 threads (4 waves = 2x2 quadrants, 2x2 frags each), 12 MFMA/K-step.
__global__ __launch_bounds__(256) void gemm_hl(
    const ushort* __restrict__ Ah_, const ushort* __restrict__ Al_,
    const ushort* __restrict__ Bh_, const ushort* __restrict__ Bl_,
    float* __restrict__ C,
    int N, int K, int lda, int ldb, int ldc, long sA, long sB, long sC) {
  Ah_ += (long)blockIdx.z * sA;
  Al_ += (long)blockIdx.z * sA;
  Bh_ += (long)blockIdx.z * sB;
  Bl_ += (long)blockIdx.z * sB;
  C += (long)blockIdx.z * sC;
  __shared__ ushort sAh[64][40], sAl[64][40], sBh[64][40], sBl[64][40];
  const int bm = blockIdx.x * 64, bn = blockIdx.y * 64;
  const int tid = threadIdx.x;
  const int wave = tid >> 6, lane = tid & 63;
  const int wm = (wave >> 1) * 32, wn = (wave & 1) * 32;
  const int srow = tid >> 2, scol = (tid & 3) * 8;
  const int fr = lane & 15, kg = (lane >> 4) * 8;
  f32x4 acc[2][2] = {};
  const int bnrow = bn + srow;
  const bool bok = bnrow < N;
  const ushort* aph = Ah_ + (long)(bm + srow) * lda + scol;
  const ushort* apl = Al_ + (long)(bm + srow) * lda + scol;
  const ushort* bph = Bh_ + (long)bnrow * ldb + scol;
  const ushort* bpl = Bl_ + (long)bnrow * ldb + scol;
  for (int k0 = 0; k0 < K; k0 += 32) {
    short8 avh = *(const short8*)(aph + k0);
    short8 avl = *(const short8*)(apl + k0);
    short8 bvh = {0, 0, 0, 0, 0, 0, 0, 0}, bvl = {0, 0, 0, 0, 0, 0, 0, 0};
    if (bok) { bvh = *(const short8*)(bph + k0); bvl = *(const short8*)(bpl + k0); }
    __syncthreads();
    *(short8*)&sAh[srow][scol] = avh;
    *(short8*)&sAl[srow][scol] = avl;
    *(short8*)&sBh[srow][scol] = bvh;
    *(short8*)&sBl[srow][scol] = bvl;
    __syncthreads();
    short8 bfh[2], bfl[2];
#pragma unroll
    for (int ni = 0; ni < 2; ni++) {
      bfh[ni] = *(const short8*)&sBh[wn + ni * 16 + fr][kg];
      bfl[ni] = *(const short8*)&sBl[wn + ni * 16 + fr][kg];
    }
#pragma unroll
    for (int mi = 0; mi < 2; mi++) {
      short8 afh = *(const short8*)&sAh[wm + mi * 16 + fr][kg];
      short8 afl = *(const short8*)&sAl[wm + mi * 16 + fr][kg];
#pragma unroll
      for (int ni = 0; ni < 2; ni++) {
        acc[mi][ni] = __builtin_amdgcn_mfma_f32_16x16x32_bf16(afh, bfh[ni], acc[mi][ni], 0, 0, 0);
        acc[mi][ni] = __builtin_amdgcn_mfma_f32_16x16x32_bf16(afh, bfl[ni], acc[mi][ni], 0, 0, 0);
        acc[mi][ni] = __builtin_amdgcn_mfma_f32_16x16x32_bf16(afl, bfh[ni], acc[mi][ni], 0, 0, 0);
      }
    }
  }
  const int row4 = (lane >> 4) * 4;
#pragma unroll
  for (int mi = 0; mi < 2; mi++)
#pragma unroll
    for (int ni = 0; ni < 2; ni++) {
      int gc = bn + wn + ni * 16 + fr;
      if (gc < N) {
        long base = (long)(bm + wm + mi * 16 + row4) * ldc + gc;
#pragma unroll
        for (int rr = 0; rr < 4; rr++) C[base + (long)rr * ldc] = acc[mi][ni][rr];
      }
    }
}

// ---------- weight prep: transpose + hi/lo split ----------
__global__ __launch_bounds__(256) void conv_bigw(const float* __restrict__ Wr,
                                                 const float* __restrict__ Wk,
                                                 const float* __restrict__ Wv,
                                                 const float* __restrict__ Wo,
                                                 ushort* __restrict__ Wb) {
  long idx = (long)blockIdx.x * 256 + threadIdx.x;  // < 4*589824
  const long WSZ = 589824;
  int seg = (int)(idx / WSZ);
  long off = idx % WSZ;
  const float* s = (seg == 0) ? Wr : (seg == 1) ? Wk : (seg == 2) ? Wv : Wo;
  PUT2(Wb, idx, 2359296L, s[off]);
}

__global__ __launch_bounds__(256) void prep_smallw(
    const float* maa_w1, const float* maa_w2, const float* wd1, const float* wd2,
    const float* a1, const float* a2, const float* kk1, const float* kk2,
    const float* g1, const float* g2, const float* ma1, const float* ma2,
    const float* mk1, const float* mk2, ushort* w1T, ushort* w2T, ushort* wcat1,
    ushort* kk1T, ushort* g1T, ushort* wd2T, ushort* armk2T, ushort* g2T) {
  int idx = blockIdx.x * 256 + threadIdx.x;
  if (idx < 98304) { int n = idx / 768, c = idx % 768; PUT2(w1T, idx, 98304, maa_w1[c * 128 + n]); return; }
  idx -= 98304;
  if (idx < 98304) {
    int f = idx / 24576, r = idx % 24576; int n = r / 32, d = r % 32;
    PUT2(w2T, idx, 98304, maa_w2[(f * 32 + d) * 768 + n]); return;
  }
  idx -= 98304;
  if (idx < 49152) { int n = idx / 768, c = idx % 768; PUT2(wcat1, idx, 86016, wd1[c * 64 + n]); return; }
  idx -= 49152;
  if (idx < 12288) { int n = idx / 768, c = idx % 768; PUT2(wcat1, 49152 + idx, 86016, a1[c * 16 + n]); return; }
  idx -= 12288;
  if (idx < 12288) { int n = idx / 768, c = idx % 768; PUT2(wcat1, 61440 + idx, 86016, ma1[c * 16 + n]); return; }
  idx -= 12288;
  if (idx < 12288) { int n = idx / 768, c = idx % 768; PUT2(wcat1, 73728 + idx, 86016, mk1[c * 16 + n]); return; }
  idx -= 12288;
  if (idx < 12288) { int n = idx / 768, c = idx % 768; PUT2(kk1T, idx, 12288, kk1[c * 16 + n]); return; }
  idx -= 12288;
  if (idx < 98304) { int n = idx / 768, c = idx % 768; PUT2(g1T, idx, 98304, g1[c * 128 + n]); return; }
  idx -= 98304;
  if (idx < 49152) { int n = idx / 64, d = idx % 64; PUT2(wd2T, idx, 49152, wd2[d * 768 + n]); return; }
  idx -= 49152;
  if (idx < 98304) {
    int f = idx / 24576, r = idx % 24576; int n = r / 32, d = r % 32;
    const float* s = (f == 0) ? a2 : (f == 1) ? ma2 : (f == 2) ? mk2 : kk2;
    float v = (d < 16) ? s[d * 768 + n] : 0.0f;
    PUT2(armk2T, idx, 98304, v); return;
  }
  idx -= 98304;
  if (idx < 98304) { int n = idx / 128, d = idx % 128; PUT2(g2T, idx, 98304, g2[d * 768 + n]); }
}

// ---------- elementwise producers (write hi/lo bf16 planes) ----------
__global__ __launch_bounds__(256) void qshift_mix(const float* __restrict__ x,
                                                  const float* __restrict__ maa_x,
                                                  float* __restrict__ xx,
                                                  ushort* __restrict__ xxxs) {
  long idx = (long)blockIdx.x * 256 + threadIdx.x;  // < BTC
  int c = (int)(idx % Cc);
  int bt = (int)(idx / Cc);
  int t = bt % Tt;
  int hh = t / WI_, ww = t % WI_;
  int q = c / 192;
  float s = 0.f;
  if (q == 0) { if (ww > 0) s = x[idx - Cc]; }
  else if (q == 1) { if (ww < WI_ - 1) s = x[idx + Cc]; }
  else if (q == 2) { if (hh > 0) s = x[idx - (long)WI_ * Cc]; }
  else { if (hh < HI_ - 1) s = x[idx + (long)WI_ * Cc]; }
  float xv = x[idx];
  float d = s - xv;
  xx[idx] = d;
  PUT2(xxxs, idx, BTC, xv + d * maa_x[c]);
}

__global__ __launch_bounds__(256) void tanh_split(const float* __restrict__ in,
                                                  ushort* __restrict__ out) {
  int i = blockIdx.x * 256 + threadIdx.x;  // 2304*128
  PUT2(out, i, 294912, tanhf(in[i]));
}

__global__ __launch_bounds__(256) void mix4(const float* __restrict__ x,
                                            const float* __restrict__ xx,
                                            const float* __restrict__ m,
                                            const float* __restrict__ maa_rg,
                                            const float* __restrict__ maa_wa,
                                            const float* __restrict__ maa_k,
                                            const float* __restrict__ maa_v,
                                            ushort* __restrict__ x4s) {
  long idx = (long)blockIdx.x * 256 + threadIdx.x;  // BTC
  int c = (int)(idx % Cc);
  float xv = x[idx], d = xx[idx];
  PUT2(x4s, idx, 4 * BTC, xv + d * (maa_rg[c] + m[idx]));                    // xrg (m0)
  PUT2(x4s, idx + BTC, 4 * BTC, xv + d * (maa_k[c] + m[idx + 2 * BTC]));     // xk  (m2)
  PUT2(x4s, idx + 2 * BTC, 4 * BTC, xv + d * (maa_v[c] + m[idx + 3 * BTC])); // xv  (m3)
  PUT2(x4s, idx + 3 * BTC, 4 * BTC, xv + d * (maa_wa[c] + m[idx + BTC]));    // xwa (m1)
}

__global__ __launch_bounds__(256) void build_a2(const float* __restrict__ wlora,
                                                const float* __restrict__ kklora,
                                                const float* __restrict__ glora,
                                                ushort* __restrict__ A2s,
                                                ushort* __restrict__ glss) {
  int idx = blockIdx.x * 256 + threadIdx.x;
  const int NA2 = 2304 * 160;
  if (idx < NA2) {
    int bt = idx / 160, col = idx % 160;
    float v;
    if (col < 64) v = tanhf(wlora[bt * 112 + col]);
    else if (col < 112) v = wlora[bt * 112 + col];
    else if (col < 128) v = tanhf(kklora[bt * 16 + (col - 112)]);
    else v = 0.0f;
    PUT2(A2s, idx, 368640, v);
    return;
  }
  idx -= NA2;
  PUT2(glss, idx, 294912, sigm(glora[idx]));  // 2304*128
}

// one wave per (bt,h); writes aa/bb/decay/k3 IN PLACE over araw/maraw/mkraw/kkraw.
__global__ __launch_bounds__(256) void post_rwkv(
    const float* __restrict__ k, const float* __restrict__ wraw, const float* __restrict__ w0,
    const float* __restrict__ a0, const float* __restrict__ ma0, const float* __restrict__ mk0,
    float* araw, float* maraw, float* mkraw, float* kkraw) {
  int gw = blockIdx.x * 4 + (threadIdx.x >> 6);  // 0..27647
  int j = threadIdx.x & 63;
  int bt = gw / Hh, h = gw % Hh;
  int c = h * 64 + j;
  long idx = (long)bt * Cc + c;
  float kv = k[idx];
  float kkv = kv + kkraw[idx];
  float ss = kkv * kkv;
  for (int mm = 1; mm < 64; mm <<= 1) ss += __shfl_xor(ss, mm, 64);
  float rn = 1.0f / fmaxf(sqrtf(ss), 1e-12f);
  float kkn = kkv * rn;
  float z = w0[c] + wraw[idx];
  float w = fminf(z, 0.f) - log1pf(__expf(-fabsf(z))) - 0.5f;
  float a = sigm(a0[c] + araw[idx]);
  float ma = sigm(ma0[c] + maraw[idx]);
  float mk = sigm(mk0[c] + mkraw[idx]);
  float k2 = kv * ma + kv * a * (1.f - ma);
  float k3 = k2 * __expf(fminf(w * mk, 0.f));
  araw[idx] = -kkn;          // aa
  maraw[idx] = kkn * a;      // bb
  mkraw[idx] = __expf(w);    // decay d
  kkraw[idx] = k3;           // final k
}

// ---------- WKV7: 48 blocks (one per (b,h)), 128 threads (2 waves), 2 rows/lane ----------
// lane = (rs, c4): rows r0 = wave*16+rs and r1 = r0+32; cols [c4*16, +16).
// Shared vectors read ONCE per lane serve both rows -> DS traffic per head halved vs 4-wave.
__global__ __launch_bounds__(128, 1) void wkv7(const float* __restrict__ r,
                                               const float* __restrict__ dd,
                                               const float* __restrict__ kk,
                                               const float* __restrict__ vv,
                                               const float* __restrict__ aa,
                                               const float* __restrict__ bb,
                                               float* __restrict__ y) {
  __shared__ float sbuf[2][6][CH][64];  // 48KB
  const int bh = blockIdx.x;
  const int b = bh / Hh, h = bh % Hh;
  const int tid = threadIdx.x;
  const int lane = tid & 63;
  const int wave = tid >> 6;
  const int rs = lane >> 2, c4 = lane & 3;
  const int r0 = wave * 16 + rs, r1 = r0 + 32;
  const int cb = c4 * 16;
  const long vecbase = ((long)b * Tt) * Cc + h * 64;
  float* py0 = y + vecbase + r0;
  float* py1 = y + vecbase + r1;
  const int st_t = tid >> 4;           // 0..7
  const int st_c = (tid & 15) * 4;
  float S0[16], S1[16];
#pragma unroll
  for (int u = 0; u < 16; u++) { S0[u] = 0.f; S1[u] = 0.f; }
  f32x4 g0[6], g1[6];

#define SLOAD(t0)                                                    \
  {                                                                  \
    long o0 = vecbase + (long)((t0) + st_t) * Cc + st_c;             \
    long o1 = o0 + 8L * Cc;                                          \
    g0[0] = *(const f32x4*)(r + o0);  g1[0] = *(const f32x4*)(r + o1);   \
    g0[1] = *(const f32x4*)(dd + o0); g1[1] = *(const f32x4*)(dd + o1);  \
    g0[2] = *(const f32x4*)(kk + o0); g1[2] = *(const f32x4*)(kk + o1);  \
    g0[3] = *(const f32x4*)(aa + o0); g1[3] = *(const f32x4*)(aa + o1);  \
    g0[4] = *(const f32x4*)(bb + o0); g1[4] = *(const f32x4*)(bb + o1);  \
    g0[5] = *(const f32x4*)(vv + o0); g1[5] = *(const f32x4*)(vv + o1);  \
  }
#define SWRITE(bi)                                                   \
  {                                                                  \
    _Pragma("unroll") for (int a_ = 0; a_ < 6; a_++) {               \
      *(f32x4*)&sbuf[bi][a_][st_t][st_c] = g0[a_];                   \
      *(f32x4*)&sbuf[bi][a_][st_t + 8][st_c] = g1[a_];               \
    }                                                                \
  }
#define WSTEP(pb, t, yoff)                                                     \
  {                                                                            \
    f32x4 Ar[4], Dr[4], Kr[4], Br[4], Rr[4];                                   \
    _Pragma("unroll") for (int u = 0; u < 4; u++)                              \
        Ar[u] = *(const f32x4*)&sbuf[pb][3][t][cb + u * 4];                    \
    float V0 = sbuf[pb][5][t][r0];                                             \
    float V1 = sbuf[pb][5][t][r1];                                             \
    _Pragma("unroll") for (int u = 0; u < 4; u++) {                            \
      Dr[u] = *(const f32x4*)&sbuf[pb][1][t][cb + u * 4];                      \
      Br[u] = *(const f32x4*)&sbuf[pb][4][t][cb + u * 4];                      \
      Kr[u] = *(const f32x4*)&sbuf[pb][2][t][cb + u * 4];                      \
      Rr[u] = *(const f32x4*)&sbuf[pb][0][t][cb + u * 4];                      \
    }                                                                          \
    float p00 = S0[0] * Ar[0][0], p01 = S0[1] * Ar[0][1];                      \
    float p02 = S0[2] * Ar[0][2], p03 = S0[3] * Ar[0][3];                      \
    float p10 = S1[0] * Ar[0][0], p11 = S1[1] * Ar[0][1];                      \
    float p12 = S1[2] * Ar[0][2], p13 = S1[3] * Ar[0][3];                      \
    _Pragma("unroll") for (int u = 1; u < 4; u++) {                            \
      p00 += S0[u * 4 + 0] * Ar[u][0]; p01 += S0[u * 4 + 1] * Ar[u][1];        \
      p02 += S0[u * 4 + 2] * Ar[u][2]; p03 += S0[u * 4 + 3] * Ar[u][3];        \
      p10 += S1[u * 4 + 0] * Ar[u][0]; p11 += S1[u * 4 + 1] * Ar[u][1];        \
      p12 += S1[u * 4 + 2] * Ar[u][2]; p13 += S1[u * 4 + 3] * Ar[u][3];        \
    }                                                                          \
    float sa0 = (p00 + p01) + (p02 + p03);                                     \
    float sa1 = (p10 + p11) + (p12 + p13);                                     \
    sa0 += __shfl_xor(sa0, 1, 64); sa1 += __shfl_xor(sa1, 1, 64);              \
    sa0 += __shfl_xor(sa0, 2, 64); sa1 += __shfl_xor(sa1, 2, 64);              \
    float q00 = 0.f, q01 = 0.f, q02 = 0.f, q03 = 0.f;                          \
    float q10 = 0.f, q11 = 0.f, q12 = 0.f, q13 = 0.f;                          \
    _Pragma("unroll") for (int u = 0; u < 4; u++) {                            \
      _Pragma("unroll") for (int e = 0; e < 4; e++) {                          \
        float s0 = S0[u * 4 + e] * Dr[u][e] + sa0 * Br[u][e] + V0 * Kr[u][e];  \
        float s1 = S1[u * 4 + e] * Dr[u][e] + sa1 * Br[u][e] + V1 * Kr[u][e];  \
        S0[u * 4 + e] = s0; S1[u * 4 + e] = s1;                                \
      }                                                                        \
      q00 += S0[u * 4 + 0] * Rr[u][0]; q01 += S0[u * 4 + 1] * Rr[u][1];        \
      q02 += S0[u * 4 + 2] * Rr[u][2]; q03 += S0[u * 4 + 3] * Rr[u][3];        \
      q10 += S1[u * 4 + 0] * Rr[u][0]; q11 += S1[u * 4 + 1] * Rr[u][1];        \
      q12 += S1[u * 4 + 2] * Rr[u][2]; q13 += S1[u * 4 + 3] * Rr[u][3];        \
    }                                                                          \
    float yp0 = (q00 + q01) + (q02 + q03);                                     \
    float yp1 = (q10 + q11) + (q12 + q13);                                     \
    yp0 += __shfl_xor(yp0, 1, 64); yp1 += __shfl_xor(yp1, 1, 64);              \
    yp0 += __shfl_xor(yp0, 2, 64); yp1 += __shfl_xor(yp1, 2, 64);              \
    if (c4 == 0) { py0[yoff] = yp0; py1[yoff] = yp1; }                         \
  }

  SLOAD(0);
  SWRITE(0);
  __syncthreads();
  SLOAD(CH);
  for (int ch = 0; ch < NCH; ch++) {
    const int pb = ch & 1;
    const long ybase = (long)ch * CH * Cc;
#pragma unroll
    for (int t = 0; t < CH; t++) WSTEP(pb, t, ybase + (long)t * Cc);
    __syncthreads();
    if (ch + 1 < NCH) {
      SWRITE(pb ^ 1);
      if (ch + 2 < NCH) SLOAD((ch + 2) * CH);
    }
    __syncthreads();
  }
#undef SLOAD
#undef SWRITE
#undef WSTEP
}

// ---------- groupnorm + bonus + gate ----------
__global__ __launch_bounds__(256) void gn_bonus_gate(
    const float* __restrict__ y, const float* __restrict__ r, const float* __restrict__ k3,
    const float* __restrict__ v, const float* __restrict__ g, const float* __restrict__ faaaa,
    const float* __restrict__ lns, const float* __restrict__ lnb, ushort* __restrict__ ygs) {
  int gw = blockIdx.x * 4 + (threadIdx.x >> 6);
  int j = threadIdx.x & 63;
  int bt = gw / Hh, h = gw % Hh;
  int c = h * 64 + j;
  long idx = (long)bt * Cc + c;
  float yv = y[idx];
  float s1 = yv, s2 = yv * yv;
  float s3 = r[idx] * k3[idx] * faaaa[c];
  for (int mm = 1; mm < 64; mm <<= 1) {
    s1 += __shfl_xor(s1, mm, 64);
    s2 += __shfl_xor(s2, mm, 64);
    s3 += __shfl_xor(s3, mm, 64);
  }
  float mu = s1 * (1.f / 64.f);
  float var = s2 * (1.f / 64.f) - mu * mu;
  float xn = (yv - mu) * rsqrtf(var + 64e-5f);
  float y2 = xn * lns[c] + lnb[c] + s3 * v[idx];
  PUT2(ygs, idx, BTC, y2 * g[idx]);
}

// ---------- launch ----------
extern "C" void kernel_launch(void* const* d_in, const int* in_sizes, int n_in,
                              void* d_out, int out_size, void* d_ws, size_t ws_size,
                              hipStream_t stream) {
  const float* x = (const float*)d_in[0];
  const float* maa_x = (const float*)d_in[1];
  const float* maa_rg = (const float*)d_in[2];
  const float* maa_wa = (const float*)d_in[3];
  const float* maa_k = (const float*)d_in[4];
  const float* maa_v = (const float*)d_in[5];
  const float* maa_w1 = (const float*)d_in[6];
  const float* maa_w2 = (const float*)d_in[7];
  const float* w0 = (const float*)d_in[8];
  const float* wd1 = (const float*)d_in[9];
  const float* wd2 = (const float*)d_in[10];
  const float* a0 = (const float*)d_in[11];
  const float* a1 = (const float*)d_in[12];
  const float* a2 = (const float*)d_in[13];
  const float* kk1 = (const float*)d_in[14];
  const float* kk2 = (const float*)d_in[15];
  const float* g1 = (const float*)d_in[16];
  const float* g2 = (const float*)d_in[17];
  const float* ma0 = (const float*)d_in[18];
  const float* ma1 = (const float*)d_in[19];
  const float* ma2 = (const float*)d_in[20];
  const float* mk0 = (const float*)d_in[21];
  const float* mk1 = (const float*)d_in[22];
  const float* mk2 = (const float*)d_in[23];
  const float* faaaa = (const float*)d_in[24];
  const float* Wr = (const float*)d_in[25];
  const float* Wk = (const float*)d_in[26];
  const float* Wv = (const float*)d_in[27];
  const float* Wo = (const float*)d_in[28];
  const float* lns = (const float*)d_in[29];
  const float* lnb = (const float*)d_in[30];

  float* fw = (float*)d_ws;
  float* xx = fw;                          // BTC
  float* m = fw + BTC;                     // 4*BTC: m0..m3, later aa/bb/dec/k3
  float* rbuf = fw + 5 * BTC;
  float* kbuf = fw + 6 * BTC;
  float* vbuf = fw + 7 * BTC;
  float* wrawb = fw + 8 * BTC;
  float* gbuf = fw + 9 * BTC;
  float* ybuf = fw + 10 * BTC;
  float* lora_raw = fw + 11 * BTC;         // 294912
  float* wlora = lora_raw + 294912;        // 258048
  float* glora = wlora + 258048;           // 294912
  float* kklora = glora + 294912;          // 36864   (sum = 884736 = BTC/2)
  ushort* ub = (ushort*)(fw + 11 * BTC + 884736);
  ushort* xxxs = ub;   ub += 2 * BTC;
  ushort* x4s = ub;    ub += 8 * BTC;
  ushort* lts = ub;    ub += 2 * 294912;
  ushort* A2s = ub;    ub += 2 * 368640;
  ushort* glss = ub;   ub += 2 * 294912;
  ushort* ygs = ub;    ub += 2 * BTC;
  ushort* Wb = ub;     ub += 2 * 2359296L;
  ushort* w1T = ub;    ub += 2 * 98304;
  ushort* w2T = ub;    ub += 2 * 98304;
  ushort* wcat1 = ub;  ub += 2 * 86016;
  ushort* kk1T = ub;   ub += 2 * 12288;
  ushort* g1T = ub;    ub += 2 * 98304;
  ushort* wd2T = ub;   ub += 2 * 49152;
  ushort* armk2T = ub; ub += 2 * 98304;
  ushort* g2T = ub;    ub += 2 * 98304;

  dim3 blk(256);
  conv_bigw<<<9216, blk, 0, stream>>>(Wr, Wk, Wv, Wo, Wb);
  prep_smallw<<<2496, blk, 0, stream>>>(maa_w1, maa_w2, wd1, wd2, a1, a2, kk1, kk2, g1, g2,
                                        ma1, ma2, mk1, mk2, w1T, w2T, wcat1, kk1T, g1T, wd2T,
                                        armk2T, g2T);
  qshift_mix<<<6912, blk, 0, stream>>>(x, maa_x, xx, xxxs);
  // lora_raw = xxx @ maa_w1  (N=128, K=768)
  gemm_hl<<<dim3(36, 2, 1), blk, 0, stream>>>(xxxs, xxxs + BTC, w1T, w1T + 98304, lora_raw,
                                              128, 768, 768, 768, 128, 0, 0, 0);
  tanh_split<<<1152, blk, 0, stream>>>(lora_raw, lts);
  // m[f] = lora[:, f*32:+32] @ maa_w2[f]  (z=4, K=32)
  gemm_hl<<<dim3(36, 12, 4), blk, 0, stream>>>(lts, lts + 294912, w2T, w2T + 98304, m,
                                               768, 32, 128, 32, 768, 32, 24576, BTC);
  mix4<<<6912, blk, 0, stream>>>(x, xx, m, maa_rg, maa_wa, maa_k, maa_v, x4s);
  // r,k,v (z=3, 768x768)
  gemm_hl<<<dim3(36, 12, 3), blk, 0, stream>>>(x4s, x4s + 4 * BTC, Wb, Wb + 2359296L, rbuf,
                                               768, 768, 768, 768, 768, BTC, 589824, BTC);
  // wlora = xwa @ [wd1|a1|ma1|mk1]  (N=112)
  gemm_hl<<<dim3(36, 2, 1), blk, 0, stream>>>(x4s + 3 * BTC, x4s + 7 * BTC, wcat1, wcat1 + 86016,
                                              wlora, 112, 768, 768, 768, 112, 0, 0, 0);
  // glora = xrg @ g1  (N=128)
  gemm_hl<<<dim3(36, 2, 1), blk, 0, stream>>>(x4s, x4s + 4 * BTC, g1T, g1T + 98304, glora,
                                              128, 768, 768, 768, 128, 0, 0, 0);
  // kklora = xk @ kk1  (N=16)
  gemm_hl<<<dim3(36, 1, 1), blk, 0, stream>>>(x4s + BTC, x4s + 5 * BTC, kk1T, kk1T + 12288,
                                              kklora, 16, 768, 768, 768, 16, 0, 0, 0);
  build_a2<<<2592, blk, 0, stream>>>(wlora, kklora, glora, A2s, glss);
  // wraw = tanh(wlora[:,0:64]) @ wd2  (K=64)
  gemm_hl<<<dim3(36, 12, 1), blk, 0, stream>>>(A2s, A2s + 368640, wd2T, wd2T + 49152, wrawb,
                                               768, 64, 160, 64, 768, 0, 0, 0);
  // araw/maraw/mkraw/kkraw  (z=4, K=32 zero-padded)
  gemm_hl<<<dim3(36, 12, 4), blk, 0, stream>>>(A2s + 64, A2s + 368640 + 64, armk2T,
                                               armk2T + 98304, m, 768, 32, 160, 32, 768,
                                               16, 24576, BTC);
  // g = sigmoid(glora) @ g2  (K=128)
  gemm_hl<<<dim3(36, 12, 1), blk, 0, stream>>>(glss, glss + 294912, g2T, g2T + 98304, gbuf,
                                               768, 128, 128, 128, 768, 0, 0, 0);
  post_rwkv<<<6912, blk, 0, stream>>>(kbuf, wrawb, w0, a0, ma0, mk0,
                                      m, m + BTC, m + 2 * BTC, m + 3 * BTC);
  wkv7<<<48, dim3(128), 0, stream>>>(rbuf, m + 2 * BTC, m + 3 * BTC, vbuf, m, m + BTC, ybuf);
  gn_bonus_gate<<<6912, blk, 0, stream>>>(ybuf, rbuf, m + 3 * BTC, vbuf, gbuf, faaaa,
                                          lns, lnb, ygs);
  // out = (y*g) @ Wo
  gemm_hl<<<dim3(36, 12, 1), blk, 0, stream>>>(ygs, ygs + BTC, Wb + 3L * 589824,
                                               Wb + 2359296L + 3L * 589824, (float*)d_out,
                                               768, 768, 768, 768, 768, 0, 0, 0);
}

// Round 6
// 471.530 us; speedup vs baseline: 2.5050x; 1.3194x over previous
//
#include <hip/hip_runtime.h>
#include <stdint.h>

#define Hh 12
#define Cc 768
#define Tt 576
#define BTC 1769472L
#define HI_ 24
#define WI_ 24
#define CH 16
#define NCH 36
#define RB 16   // rows per wkv7 block
#define NRB 4   // row-blocks per head

typedef unsigned int uint;
typedef unsigned short ushort;
typedef __attribute__((ext_vector_type(8))) short short8;
typedef __attribute__((ext_vector_type(4))) float f32x4;

__device__ __forceinline__ ushort f2b(float f) {
  uint u = __float_as_uint(f);
  u += 0x7FFFu + ((u >> 16) & 1u);
  return (ushort)(u >> 16);
}
__device__ __forceinline__ float b2f(ushort h) { return __uint_as_float(((uint)h) << 16); }
__device__ __forceinline__ float sigm(float x) { return 1.0f / (1.0f + __expf(-x)); }

// cross-lane helpers: xor1/xor2 via DPP quad_perm (VALU pipe), xor4 via ds_swizzle
__device__ __forceinline__ float dppx1(float x) {
  return __int_as_float(__builtin_amdgcn_mov_dpp(__float_as_int(x), 0xB1, 0xF, 0xF, true));
}
__device__ __forceinline__ float dppx2(float x) {
  return __int_as_float(__builtin_amdgcn_mov_dpp(__float_as_int(x), 0x4E, 0xF, 0xF, true));
}
__device__ __forceinline__ float swz4(float x) {
  return __int_as_float(__builtin_amdgcn_ds_swizzle(__float_as_int(x), 0x101F));
}

// hi/lo convention: every bf16-split buffer holds hi plane at [0, SZ) and lo plane at [SZ, 2*SZ).
#define PUT2(buf, i, SZ, vexpr)                      \
  {                                                  \
    float _v = (vexpr);                              \
    ushort _h = f2b(_v);                             \
    (buf)[i] = _h;                                   \
    (buf)[(long)(SZ) + (i)] = f2b(_v - b2f(_h));     \
  }

// ---------- GEMM: C[M,N] = A[M,K] @ B[N,K]^T; A,B pre-split bf16 hi/lo; C fp32 ----------
// 64x64 tile, BK=32, 256 threads (4 waves = 2x2 quadrants, 2x2 frags each), 12 MFMA/K-step.
__global__ __launch_bounds__(256) void gemm_hl(
    const ushort* __restrict__ Ah_, const ushort* __restrict__ Al_,
    const ushort* __restrict__ Bh_, const ushort* __restrict__ Bl_,
    float* __restrict__ C,
    int N, int K, int lda, int ldb, int ldc, long sA, long sB, long sC) {
  Ah_ += (long)blockIdx.z * sA;
  Al_ += (long)blockIdx.z * sA;
  Bh_ += (long)blockIdx.z * sB;
  Bl_ += (long)blockIdx.z * sB;
  C += (long)blockIdx.z * sC;
  __shared__ ushort sAh[64][40], sAl[64][40], sBh[64][40], sBl[64][40];
  const int bm = blockIdx.x * 64, bn = blockIdx.y * 64;
  const int tid = threadIdx.x;
  const int wave = tid >> 6, lane = tid & 63;
  const int wm = (wave >> 1) * 32, wn = (wave & 1) * 32;
  const int srow = tid >> 2, scol = (tid & 3) * 8;
  const int fr = lane & 15, kg = (lane >> 4) * 8;
  f32x4 acc[2][2] = {};
  const int bnrow = bn + srow;
  const bool bok = bnrow < N;
  const ushort* aph = Ah_ + (long)(bm + srow) * lda + scol;
  const ushort* apl = Al_ + (long)(bm + srow) * lda + scol;
  const ushort* bph = Bh_ + (long)bnrow * ldb + scol;
  const ushort* bpl = Bl_ + (long)bnrow * ldb + scol;
  for (int k0 = 0; k0 < K; k0 += 32) {
    short8 avh = *(const short8*)(aph + k0);
    short8 avl = *(const short8*)(apl + k0);
    short8 bvh = {0, 0, 0, 0, 0, 0, 0, 0}, bvl = {0, 0, 0, 0, 0, 0, 0, 0};
    if (bok) { bvh = *(const short8*)(bph + k0); bvl = *(const short8*)(bpl + k0); }
    __syncthreads();
    *(short8*)&sAh[srow][scol] = avh;
    *(short8*)&sAl[srow][scol] = avl;
    *(short8*)&sBh[srow][scol] = bvh;
    *(short8*)&sBl[srow][scol] = bvl;
    __syncthreads();
    short8 bfh[2], bfl[2];
#pragma unroll
    for (int ni = 0; ni < 2; ni++) {
      bfh[ni] = *(const short8*)&sBh[wn + ni * 16 + fr][kg];
      bfl[ni] = *(const short8*)&sBl[wn + ni * 16 + fr][kg];
    }
#pragma unroll
    for (int mi = 0; mi < 2; mi++) {
      short8 afh = *(const short8*)&sAh[wm + mi * 16 + fr][kg];
      short8 afl = *(const short8*)&sAl[wm + mi * 16 + fr][kg];
#pragma unroll
      for (int ni = 0; ni < 2; ni++) {
        acc[mi][ni] = __builtin_amdgcn_mfma_f32_16x16x32_bf16(afh, bfh[ni], acc[mi][ni], 0, 0, 0);
        acc[mi][ni] = __builtin_amdgcn_mfma_f32_16x16x32_bf16(afh, bfl[ni], acc[mi][ni], 0, 0, 0);
        acc[mi][ni] = __builtin_amdgcn_mfma_f32_16x16x32_bf16(afl, bfh[ni], acc[mi][ni], 0, 0, 0);
      }
    }
  }
  const int row4 = (lane >> 4) * 4;
#pragma unroll
  for (int mi = 0; mi < 2; mi++)
#pragma unroll
    for (int ni = 0; ni < 2; ni++) {
      int gc = bn + wn + ni * 16 + fr;
      if (gc < N) {
        long base = (long)(bm + wm + mi * 16 + row4) * ldc + gc;
#pragma unroll
        for (int rr = 0; rr < 4; rr++) C[base + (long)rr * ldc] = acc[mi][ni][rr];
      }
    }
}

// ---------- weight prep: transpose + hi/lo split ----------
__global__ __launch_bounds__(256) void conv_bigw(const float* __restrict__ Wr,
                                                 const float* __restrict__ Wk,
                                                 const float* __restrict__ Wv,
                                                 const float* __restrict__ Wo,
                                                 ushort* __restrict__ Wb) {
  long idx = (long)blockIdx.x * 256 + threadIdx.x;  // < 4*589824
  const long WSZ = 589824;
  int seg = (int)(idx / WSZ);
  long off = idx % WSZ;
  const float* s = (seg == 0) ? Wr : (seg == 1) ? Wk : (seg == 2) ? Wv : Wo;
  PUT2(Wb, idx, 2359296L, s[off]);
}

__global__ __launch_bounds__(256) void prep_smallw(
    const float* maa_w1, const float* maa_w2, const float* wd1, const float* wd2,
    const float* a1, const float* a2, const float* kk1, const float* kk2,
    const float* g1, const float* g2, const float* ma1, const float* ma2,
    const float* mk1, const float* mk2, ushort* w1T, ushort* w2T, ushort* wcat1,
    ushort* kk1T, ushort* g1T, ushort* wd2T, ushort* armk2T, ushort* g2T) {
  int idx = blockIdx.x * 256 + threadIdx.x;
  if (idx < 98304) { int n = idx / 768, c = idx % 768; PUT2(w1T, idx, 98304, maa_w1[c * 128 + n]); return; }
  idx -= 98304;
  if (idx < 98304) {
    int f = idx / 24576, r = idx % 24576; int n = r / 32, d = r % 32;
    PUT2(w2T, idx, 98304, maa_w2[(f * 32 + d) * 768 + n]); return;
  }
  idx -= 98304;
  if (idx < 49152) { int n = idx / 768, c = idx % 768; PUT2(wcat1, idx, 86016, wd1[c * 64 + n]); return; }
  idx -= 49152;
  if (idx < 12288) { int n = idx / 768, c = idx % 768; PUT2(wcat1, 49152 + idx, 86016, a1[c * 16 + n]); return; }
  idx -= 12288;
  if (idx < 12288) { int n = idx / 768, c = idx % 768; PUT2(wcat1, 61440 + idx, 86016, ma1[c * 16 + n]); return; }
  idx -= 12288;
  if (idx < 12288) { int n = idx / 768, c = idx % 768; PUT2(wcat1, 73728 + idx, 86016, mk1[c * 16 + n]); return; }
  idx -= 12288;
  if (idx < 12288) { int n = idx / 768, c = idx % 768; PUT2(kk1T, idx, 12288, kk1[c * 16 + n]); return; }
  idx -= 12288;
  if (idx < 98304) { int n = idx / 768, c = idx % 768; PUT2(g1T, idx, 98304, g1[c * 128 + n]); return; }
  idx -= 98304;
  if (idx < 49152) { int n = idx / 64, d = idx % 64; PUT2(wd2T, idx, 49152, wd2[d * 768 + n]); return; }
  idx -= 49152;
  if (idx < 98304) {
    int f = idx / 24576, r = idx % 24576; int n = r / 32, d = r % 32;
    const float* s = (f == 0) ? a2 : (f == 1) ? ma2 : (f == 2) ? mk2 : kk2;
    float v = (d < 16) ? s[d * 768 + n] : 0.0f;
    PUT2(armk2T, idx, 98304, v); return;
  }
  idx -= 98304;
  if (idx < 98304) { int n = idx / 128, d = idx % 128; PUT2(g2T, idx, 98304, g2[d * 768 + n]); }
}

// ---------- elementwise producers (write hi/lo bf16 planes) ----------
__global__ __launch_bounds__(256) void qshift_mix(const float* __restrict__ x,
                                                  const float* __restrict__ maa_x,
                                                  float* __restrict__ xx,
                                                  ushort* __restrict__ xxxs) {
  long idx = (long)blockIdx.x * 256 + threadIdx.x;  // < BTC
  int c = (int)(idx % Cc);
  int bt = (int)(idx / Cc);
  int t = bt % Tt;
  int hh = t / WI_, ww = t % WI_;
  int q = c / 192;
  float s = 0.f;
  if (q == 0) { if (ww > 0) s = x[idx - Cc]; }
  else if (q == 1) { if (ww < WI_ - 1) s = x[idx + Cc]; }
  else if (q == 2) { if (hh > 0) s = x[idx - (long)WI_ * Cc]; }
  else { if (hh < HI_ - 1) s = x[idx + (long)WI_ * Cc]; }
  float xv = x[idx];
  float d = s - xv;
  xx[idx] = d;
  PUT2(xxxs, idx, BTC, xv + d * maa_x[c]);
}

__global__ __launch_bounds__(256) void tanh_split(const float* __restrict__ in,
                                                  ushort* __restrict__ out) {
  int i = blockIdx.x * 256 + threadIdx.x;  // 2304*128
  PUT2(out, i, 294912, tanhf(in[i]));
}

__global__ __launch_bounds__(256) void mix4(const float* __restrict__ x,
                                            const float* __restrict__ xx,
                                            const float* __restrict__ m,
                                            const float* __restrict__ maa_rg,
                                            const float* __restrict__ maa_wa,
                                            const float* __restrict__ maa_k,
                                            const float* __restrict__ maa_v,
                                            ushort* __restrict__ x4s) {
  long idx = (long)blockIdx.x * 256 + threadIdx.x;  // BTC
  int c = (int)(idx % Cc);
  float xv = x[idx], d = xx[idx];
  PUT2(x4s, idx, 4 * BTC, xv + d * (maa_rg[c] + m[idx]));                    // xrg (m0)
  PUT2(x4s, idx + BTC, 4 * BTC, xv + d * (maa_k[c] + m[idx + 2 * BTC]));     // xk  (m2)
  PUT2(x4s, idx + 2 * BTC, 4 * BTC, xv + d * (maa_v[c] + m[idx + 3 * BTC])); // xv  (m3)
  PUT2(x4s, idx + 3 * BTC, 4 * BTC, xv + d * (maa_wa[c] + m[idx + BTC]));    // xwa (m1)
}

__global__ __launch_bounds__(256) void build_a2(const float* __restrict__ wlora,
                                                const float* __restrict__ kklora,
                                                const float* __restrict__ glora,
                                                ushort* __restrict__ A2s,
                                                ushort* __restrict__ glss) {
  int idx = blockIdx.x * 256 + threadIdx.x;
  const int NA2 = 2304 * 160;
  if (idx < NA2) {
    int bt = idx / 160, col = idx % 160;
    float v;
    if (col < 64) v = tanhf(wlora[bt * 112 + col]);
    else if (col < 112) v = wlora[bt * 112 + col];
    else if (col < 128) v = tanhf(kklora[bt * 16 + (col - 112)]);
    else v = 0.0f;
    PUT2(A2s, idx, 368640, v);
    return;
  }
  idx -= NA2;
  PUT2(glss, idx, 294912, sigm(glora[idx]));  // 2304*128
}

// one wave per (bt,h); writes aa/bb/decay/k3 IN PLACE over araw/maraw/mkraw/kkraw.
__global__ __launch_bounds__(256) void post_rwkv(
    const float* __restrict__ k, const float* __restrict__ wraw, const float* __restrict__ w0,
    const float* __restrict__ a0, const float* __restrict__ ma0, const float* __restrict__ mk0,
    float* araw, float* maraw, float* mkraw, float* kkraw) {
  int gw = blockIdx.x * 4 + (threadIdx.x >> 6);  // 0..27647
  int j = threadIdx.x & 63;
  int bt = gw / Hh, h = gw % Hh;
  int c = h * 64 + j;
  long idx = (long)bt * Cc + c;
  float kv = k[idx];
  float kkv = kv + kkraw[idx];
  float ss = kkv * kkv;
  for (int mm = 1; mm < 64; mm <<= 1) ss += __shfl_xor(ss, mm, 64);
  float rn = 1.0f / fmaxf(sqrtf(ss), 1e-12f);
  float kkn = kkv * rn;
  float z = w0[c] + wraw[idx];
  float w = fminf(z, 0.f) - log1pf(__expf(-fabsf(z))) - 0.5f;
  float a = sigm(a0[c] + araw[idx]);
  float ma = sigm(ma0[c] + maraw[idx]);
  float mk = sigm(mk0[c] + mkraw[idx]);
  float k2 = kv * ma + kv * a * (1.f - ma);
  float k3 = k2 * __expf(fminf(w * mk, 0.f));
  araw[idx] = -kkn;          // aa
  maraw[idx] = kkn * a;      // bb
  mkraw[idx] = __expf(w);    // decay d
  kkraw[idx] = k3;           // final k
}

// ---------- WKV7: ROW-SPLIT. 192 blocks (= 48 heads x 4 row-blocks), 128 threads ----------
// Rows of S are independent: block handles 16 rows of one head; each CU stages the shared
// column-vectors (r,d,k,a,b) redundantly but serves only 2 waves -> per-CU DS ~270cy/step.
// Wave layout: 8 rows x 8 lanes/row; lane owns 8 cols (S[8] regs). sa/y reduced over 8 lanes
// via DPP quad_perm (xor1/xor2, VALU pipe) + ds_swizzle (xor4).
__global__ __launch_bounds__(128, 1) void wkv7(const float* __restrict__ r,
                                               const float* __restrict__ dd,
                                               const float* __restrict__ kk,
                                               const float* __restrict__ vv,
                                               const float* __restrict__ aa,
                                               const float* __restrict__ bb,
                                               float* __restrict__ y) {
  __shared__ float sc[2][5][CH][64];  // r,d,k,a,b full col-vectors: 40KB
  __shared__ float sv[2][CH][RB];     // v slice for this block's rows: 2KB
  const int blk = blockIdx.x;
  const int bh = blk >> 2;            // head 0..47
  const int rb = blk & 3;             // row-block 0..3
  const int b = bh / Hh, h = bh % Hh;
  const int tid = threadIdx.x;
  const int wave = tid >> 6, lane = tid & 63;
  const int rl = lane >> 3, cg = lane & 7;
  const int row = rb * RB + wave * 8 + rl;   // global state row 0..63
  const int cb = cg * 8;                     // cols [cb, cb+8)
  const int vri = wave * 8 + rl;             // local row in sv
  const long vecbase = ((long)b * Tt) * Cc + h * 64;
  float* py = y + vecbase + row;
  const float* gp[5] = {r, dd, kk, aa, bb};
  float S[8];
#pragma unroll
  for (int u = 0; u < 8; u++) S[u] = 0.f;
  f32x4 gq[10];
  float gv[2];

#define SLOAD(t0)                                                              \
  {                                                                            \
    _Pragma("unroll") for (int q = 0; q < 10; q++) {                           \
      const int arr = q >> 1;                                                  \
      const int i2 = ((q & 1) << 7) + tid;                                     \
      gq[q] = *(const f32x4*)(gp[arr] + vecbase + (long)((t0) + (i2 >> 4)) * Cc \
                              + ((i2 & 15) << 2));                             \
    }                                                                          \
    _Pragma("unroll") for (int j = 0; j < 2; j++) {                            \
      const int i2 = (j << 7) + tid;                                           \
      gv[j] = vv[vecbase + (long)((t0) + (i2 >> 4)) * Cc + rb * RB + (i2 & 15)]; \
    }                                                                          \
  }
#define SWRITE(bi)                                                             \
  {                                                                            \
    _Pragma("unroll") for (int q = 0; q < 10; q++) {                           \
      const int i2 = ((q & 1) << 7) + tid;                                     \
      *(f32x4*)&sc[bi][q >> 1][i2 >> 4][(i2 & 15) << 2] = gq[q];               \
    }                                                                          \
    _Pragma("unroll") for (int j = 0; j < 2; j++) {                            \
      const int i2 = (j << 7) + tid;                                           \
      sv[bi][i2 >> 4][i2 & 15] = gv[j];                                        \
    }                                                                          \
  }
#define WSTEP(pb, t, yoff)                                                     \
  {                                                                            \
    f32x4 A0 = *(const f32x4*)&sc[pb][3][t][cb];                               \
    f32x4 A1 = *(const f32x4*)&sc[pb][3][t][cb + 4];                           \
    f32x4 D0 = *(const f32x4*)&sc[pb][1][t][cb];                               \
    f32x4 D1 = *(const f32x4*)&sc[pb][1][t][cb + 4];                           \
    f32x4 K0 = *(const f32x4*)&sc[pb][2][t][cb];                               \
    f32x4 K1 = *(const f32x4*)&sc[pb][2][t][cb + 4];                           \
    f32x4 B0 = *(const f32x4*)&sc[pb][4][t][cb];                               \
    f32x4 B1 = *(const f32x4*)&sc[pb][4][t][cb + 4];                           \
    f32x4 R0 = *(const f32x4*)&sc[pb][0][t][cb];                               \
    f32x4 R1 = *(const f32x4*)&sc[pb][0][t][cb + 4];                           \
    float V = sv[pb][t][vri];                                                  \
    float p0 = S[0] * A0[0] + S[4] * A1[0];                                    \
    float p1 = S[1] * A0[1] + S[5] * A1[1];                                    \
    float p2 = S[2] * A0[2] + S[6] * A1[2];                                    \
    float p3 = S[3] * A0[3] + S[7] * A1[3];                                    \
    float sa = (p0 + p1) + (p2 + p3);                                          \
    sa += dppx1(sa); sa += dppx2(sa); sa += swz4(sa);                          \
    float q0, q1, q2, q3;                                                      \
    S[0] = fmaf(S[0], D0[0], fmaf(sa, B0[0], V * K0[0])); q0 = S[0] * R0[0];   \
    S[1] = fmaf(S[1], D0[1], fmaf(sa, B0[1], V * K0[1])); q1 = S[1] * R0[1];   \
    S[2] = fmaf(S[2], D0[2], fmaf(sa, B0[2], V * K0[2])); q2 = S[2] * R0[2];   \
    S[3] = fmaf(S[3], D0[3], fmaf(sa, B0[3], V * K0[3])); q3 = S[3] * R0[3];   \
    S[4] = fmaf(S[4], D1[0], fmaf(sa, B1[0], V * K1[0])); q0 += S[4] * R1[0];  \
    S[5] = fmaf(S[5], D1[1], fmaf(sa, B1[1], V * K1[1])); q1 += S[5] * R1[1];  \
    S[6] = fmaf(S[6], D1[2], fmaf(sa, B1[2], V * K1[2])); q2 += S[6] * R1[2];  \
    S[7] = fmaf(S[7], D1[3], fmaf(sa, B1[3], V * K1[3])); q3 += S[7] * R1[3];  \
    float yp = (q0 + q1) + (q2 + q3);                                          \
    yp += dppx1(yp); yp += dppx2(yp); yp += swz4(yp);                          \
    if (cg == 0) py[yoff] = yp;                                                \
  }

  SLOAD(0);
  SWRITE(0);
  __syncthreads();
  SLOAD(CH);
  for (int ch = 0; ch < NCH; ch++) {
    const int pb = ch & 1;
    const long ybase = (long)ch * CH * Cc;
#pragma unroll
    for (int t = 0; t < CH; t++) WSTEP(pb, t, ybase + (long)t * Cc);
    __syncthreads();
    if (ch + 1 < NCH) {
      SWRITE(pb ^ 1);
      if (ch + 2 < NCH) SLOAD((ch + 2) * CH);
    }
    __syncthreads();
  }
#undef SLOAD
#undef SWRITE
#undef WSTEP
}

// ---------- groupnorm + bonus + gate ----------
__global__ __launch_bounds__(256) void gn_bonus_gate(
    const float* __restrict__ y, const float* __restrict__ r, const float* __restrict__ k3,
    const float* __restrict__ v, const float* __restrict__ g, const float* __restrict__ faaaa,
    const float* __restrict__ lns, const float* __restrict__ lnb, ushort* __restrict__ ygs) {
  int gw = blockIdx.x * 4 + (threadIdx.x >> 6);
  int j = threadIdx.x & 63;
  int bt = gw / Hh, h = gw % Hh;
  int c = h * 64 + j;
  long idx = (long)bt * Cc + c;
  float yv = y[idx];
  float s1 = yv, s2 = yv * yv;
  float s3 = r[idx] * k3[idx] * faaaa[c];
  for (int mm = 1; mm < 64; mm <<= 1) {
    s1 += __shfl_xor(s1, mm, 64);
    s2 += __shfl_xor(s2, mm, 64);
    s3 += __shfl_xor(s3, mm, 64);
  }
  float mu = s1 * (1.f / 64.f);
  float var = s2 * (1.f / 64.f) - mu * mu;
  float xn = (yv - mu) * rsqrtf(var + 64e-5f);
  float y2 = xn * lns[c] + lnb[c] + s3 * v[idx];
  PUT2(ygs, idx, BTC, y2 * g[idx]);
}

// ---------- launch ----------
extern "C" void kernel_launch(void* const* d_in, const int* in_sizes, int n_in,
                              void* d_out, int out_size, void* d_ws, size_t ws_size,
                              hipStream_t stream) {
  const float* x = (const float*)d_in[0];
  const float* maa_x = (const float*)d_in[1];
  const float* maa_rg = (const float*)d_in[2];
  const float* maa_wa = (const float*)d_in[3];
  const float* maa_k = (const float*)d_in[4];
  const float* maa_v = (const float*)d_in[5];
  const float* maa_w1 = (const float*)d_in[6];
  const float* maa_w2 = (const float*)d_in[7];
  const float* w0 = (const float*)d_in[8];
  const float* wd1 = (const float*)d_in[9];
  const float* wd2 = (const float*)d_in[10];
  const float* a0 = (const float*)d_in[11];
  const float* a1 = (const float*)d_in[12];
  const float* a2 = (const float*)d_in[13];
  const float* kk1 = (const float*)d_in[14];
  const float* kk2 = (const float*)d_in[15];
  const float* g1 = (const float*)d_in[16];
  const float* g2 = (const float*)d_in[17];
  const float* ma0 = (const float*)d_in[18];
  const float* ma1 = (const float*)d_in[19];
  const float* ma2 = (const float*)d_in[20];
  const float* mk0 = (const float*)d_in[21];
  const float* mk1 = (const float*)d_in[22];
  const float* mk2 = (const float*)d_in[23];
  const float* faaaa = (const float*)d_in[24];
  const float* Wr = (const float*)d_in[25];
  const float* Wk = (const float*)d_in[26];
  const float* Wv = (const float*)d_in[27];
  const float* Wo = (const float*)d_in[28];
  const float* lns = (const float*)d_in[29];
  const float* lnb = (const float*)d_in[30];

  float* fw = (float*)d_ws;
  float* xx = fw;                          // BTC
  float* m = fw + BTC;                     // 4*BTC: m0..m3, later aa/bb/dec/k3
  float* rbuf = fw + 5 * BTC;
  float* kbuf = fw + 6 * BTC;
  float* vbuf = fw + 7 * BTC;
  float* wrawb = fw + 8 * BTC;
  float* gbuf = fw + 9 * BTC;
  float* ybuf = fw + 10 * BTC;
  float* lora_raw = fw + 11 * BTC;         // 294912
  float* wlora = lora_raw + 294912;        // 258048
  float* glora = wlora + 258048;           // 294912
  float* kklora = glora + 294912;          // 36864   (sum = 884736 = BTC/2)
  ushort* ub = (ushort*)(fw + 11 * BTC + 884736);
  ushort* xxxs = ub;   ub += 2 * BTC;
  ushort* x4s = ub;    ub += 8 * BTC;
  ushort* lts = ub;    ub += 2 * 294912;
  ushort* A2s = ub;    ub += 2 * 368640;
  ushort* glss = ub;   ub += 2 * 294912;
  ushort* ygs = ub;    ub += 2 * BTC;
  ushort* Wb = ub;     ub += 2 * 2359296L;
  ushort* w1T = ub;    ub += 2 * 98304;
  ushort* w2T = ub;    ub += 2 * 98304;
  ushort* wcat1 = ub;  ub += 2 * 86016;
  ushort* kk1T = ub;   ub += 2 * 12288;
  ushort* g1T = ub;    ub += 2 * 98304;
  ushort* wd2T = ub;   ub += 2 * 49152;
  ushort* armk2T = ub; ub += 2 * 98304;
  ushort* g2T = ub;    ub += 2 * 98304;

  dim3 blk(256);
  conv_bigw<<<9216, blk, 0, stream>>>(Wr, Wk, Wv, Wo, Wb);
  prep_smallw<<<2496, blk, 0, stream>>>(maa_w1, maa_w2, wd1, wd2, a1, a2, kk1, kk2, g1, g2,
                                        ma1, ma2, mk1, mk2, w1T, w2T, wcat1, kk1T, g1T, wd2T,
                                        armk2T, g2T);
  qshift_mix<<<6912, blk, 0, stream>>>(x, maa_x, xx, xxxs);
  // lora_raw = xxx @ maa_w1  (N=128, K=768)
  gemm_hl<<<dim3(36, 2, 1), blk, 0, stream>>>(xxxs, xxxs + BTC, w1T, w1T + 98304, lora_raw,
                                              128, 768, 768, 768, 128, 0, 0, 0);
  tanh_split<<<1152, blk, 0, stream>>>(lora_raw, lts);
  // m[f] = lora[:, f*32:+32] @ maa_w2[f]  (z=4, K=32)
  gemm_hl<<<dim3(36, 12, 4), blk, 0, stream>>>(lts, lts + 294912, w2T, w2T + 98304, m,
                                               768, 32, 128, 32, 768, 32, 24576, BTC);
  mix4<<<6912, blk, 0, stream>>>(x, xx, m, maa_rg, maa_wa, maa_k, maa_v, x4s);
  // r,k,v (z=3, 768x768)
  gemm_hl<<<dim3(36, 12, 3), blk, 0, stream>>>(x4s, x4s + 4 * BTC, Wb, Wb + 2359296L, rbuf,
                                               768, 768, 768, 768, 768, BTC, 589824, BTC);
  // wlora = xwa @ [wd1|a1|ma1|mk1]  (N=112)
  gemm_hl<<<dim3(36, 2, 1), blk, 0, stream>>>(x4s + 3 * BTC, x4s + 7 * BTC, wcat1, wcat1 + 86016,
                                              wlora, 112, 768, 768, 768, 112, 0, 0, 0);
  // glora = xrg @ g1  (N=128)
  gemm_hl<<<dim3(36, 2, 1), blk, 0, stream>>>(x4s, x4s + 4 * BTC, g1T, g1T + 98304, glora,
                                              128, 768, 768, 768, 128, 0, 0, 0);
  // kklora = xk @ kk1  (N=16)
  gemm_hl<<<dim3(36, 1, 1), blk, 0, stream>>>(x4s + BTC, x4s + 5 * BTC, kk1T, kk1T + 12288,
                                              kklora, 16, 768, 768, 768, 16, 0, 0, 0);
  build_a2<<<2592, blk, 0, stream>>>(wlora, kklora, glora, A2s, glss);
  // wraw = tanh(wlora[:,0:64]) @ wd2  (K=64)
  gemm_hl<<<dim3(36, 12, 1), blk, 0, stream>>>(A2s, A2s + 368640, wd2T, wd2T + 49152, wrawb,
                                               768, 64, 160, 64, 768, 0, 0, 0);
  // araw/maraw/mkraw/kkraw  (z=4, K=32 zero-padded)
  gemm_hl<<<dim3(36, 12, 4), blk, 0, stream>>>(A2s + 64, A2s + 368640 + 64, armk2T,
                                               armk2T + 98304, m, 768, 32, 160, 32, 768,
                                               16, 24576, BTC);
  // g = sigmoid(glora) @ g2  (K=128)
  gemm_hl<<<dim3(36, 12, 1), blk, 0, stream>>>(glss, glss + 294912, g2T, g2T + 98304, gbuf,
                                               768, 128, 128, 128, 768, 0, 0, 0);
  post_rwkv<<<6912, blk, 0, stream>>>(kbuf, wrawb, w0, a0, ma0, mk0,
                                      m, m + BTC, m + 2 * BTC, m + 3 * BTC);
  wkv7<<<192, dim3(128), 0, stream>>>(rbuf, m + 2 * BTC, m + 3 * BTC, vbuf, m, m + BTC, ybuf);
  gn_bonus_gate<<<6912, blk, 0, stream>>>(ybuf, rbuf, m + 3 * BTC, vbuf, gbuf, faaaa,
                                          lns, lnb, ygs);
  // out = (y*g) @ Wo
  gemm_hl<<<dim3(36, 12, 1), blk, 0, stream>>>(ygs, ygs + BTC, Wb + 3L * 589824,
                                               Wb + 2359296L + 3L * 589824, (float*)d_out,
                                               768, 768, 768, 768, 768, 0, 0, 0);
}